// Round 14
// baseline (314.647 us; speedup 1.0000x reference)
//
#include <hip/hip_runtime.h>
#include <hip/hip_cooperative_groups.h>
#include <cstddef>

namespace cg = cooperative_groups;

#define B_      4
#define N_      1024
#define DIM_    512
#define H_      8
#define D_      64
#define INNER_  512
#define TRIPLE_ 1536
#define KK_     716        // int(1024 * 0.7)
#define SCALE_  0.125f     // 64^-0.5

typedef short bf16x8 __attribute__((ext_vector_type(8)));
typedef float f32x4  __attribute__((ext_vector_type(4)));
typedef unsigned short ushort_t;
typedef ushort_t us8 __attribute__((ext_vector_type(8)));

__device__ __forceinline__ unsigned short bf16_rne(float f) {
    unsigned u = __float_as_uint(f);
    return (unsigned short)((u + 0x7FFFu + ((u >> 16) & 1u)) >> 16);
}
__device__ __forceinline__ float bf16_f(unsigned short s) {
    return __uint_as_float((unsigned)s << 16);
}
// order-preserving float->uint key (descending float == descending uint)
__device__ __forceinline__ unsigned f2key(float f) {
    unsigned u = __float_as_uint(f);
    return u ^ ((u & 0x80000000u) ? 0xFFFFFFFFu : 0x80000000u);
}
__device__ __forceinline__ float key2f(unsigned k) {
    unsigned u = (k & 0x80000000u) ? (k ^ 0x80000000u) : ~k;
    return __uint_as_float(u);
}
// wave-wide count of per-lane tallies lc in [0,16] via 5 bit-plane ballots
__device__ __forceinline__ int wave_count(int lc) {
    int c = __popcll(__ballot(lc & 1));
    c += __popcll(__ballot(lc & 2)) << 1;
    c += __popcll(__ballot(lc & 4)) << 2;
    c += __popcll(__ballot(lc & 8)) << 3;
    c += __popcll(__ballot(lc & 16)) << 4;
    return c;
}
__device__ __forceinline__ int count_ge(const unsigned* key, unsigned kt) {
    int lc = 0;
#pragma unroll
    for (int m = 0; m < 16; ++m) lc += (key[m] >= kt) ? 1 : 0;
    return wave_count(lc);
}
// guaranteed-exact uint bisection fallback (rare path)
__device__ __forceinline__ unsigned bisect_exact(const unsigned* key,
                                                 bool hlo, bool hhi,
                                                 float tlo, float thi) {
    unsigned klo = hlo ? f2key(tlo) : 0u;
    unsigned khi = hhi ? f2key(thi) : 0xFFFFFFFFu;
    while (khi - klo > 1u) {
        const unsigned km = klo + ((khi - klo) >> 1);
        const int c = count_ge(key, km);
        if (c >= KK_) { klo = km; if (c == KK_) break; }
        else khi = km;
    }
    return klo;
}
// dual-row interpolation-seeded secant search, chains interleaved for latency
__device__ __forceinline__ void topk2(const unsigned* key0, const unsigned* key1,
                                      float mu0, float sg0, float mu1, float sg1,
                                      unsigned& out0, unsigned& out1) {
    bool done0 = false, done1 = false;
    float tlo0 = 0.f, thi0 = 0.f, tlo1 = 0.f, thi1 = 0.f;
    int   clo0 = 0,   chi0 = 0,   clo1 = 0,   chi1 = 0;
    bool  hlo0 = false, hhi0 = false, hlo1 = false, hhi1 = false;
    float t0 = mu0 - 0.52189f * sg0;      // seed at the 716/1024 quantile
    float t1 = mu1 - 0.52189f * sg1;
    unsigned res0 = 0u, res1 = 0u;
    for (int it = 0; it < 10; ++it) {
        if (done0 & done1) break;
        const unsigned kt0 = f2key(t0);
        const unsigned kt1 = f2key(t1);
        int lc0 = 0, lc1 = 0;
#pragma unroll
        for (int m = 0; m < 16; ++m) {
            lc0 += (key0[m] >= kt0) ? 1 : 0;
            lc1 += (key1[m] >= kt1) ? 1 : 0;
        }
        const int c0 = wave_count(lc0);
        const int c1 = wave_count(lc1);
        if (!done0) {
            if (c0 == KK_) { res0 = kt0; done0 = true; }
            else {
                if (c0 > KK_) { tlo0 = t0; clo0 = c0; hlo0 = true; }
                else          { thi0 = t0; chi0 = c0; hhi0 = true; }
                float tn;
                if (hlo0 && hhi0) {
                    tn = tlo0 + (thi0 - tlo0) * ((float)(clo0 - KK_) / (float)(clo0 - chi0));
                } else {
                    const float z    = (t0 - mu0) / sg0;
                    const float dens = fmaxf(408.5f * __expf(-0.5f * z * z) / sg0, 1.f);
                    tn = t0 + (float)(c0 - KK_) / dens;
                }
                if (hlo0 && !(tn > tlo0)) tn = hhi0 ? 0.5f * (tlo0 + thi0) : tlo0 + 0.25f * sg0;
                if (hhi0 && !(tn < thi0)) tn = hlo0 ? 0.5f * (tlo0 + thi0) : thi0 - 0.25f * sg0;
                t0 = tn;
            }
        }
        if (!done1) {
            if (c1 == KK_) { res1 = kt1; done1 = true; }
            else {
                if (c1 > KK_) { tlo1 = t1; clo1 = c1; hlo1 = true; }
                else          { thi1 = t1; chi1 = c1; hhi1 = true; }
                float tn;
                if (hlo1 && hhi1) {
                    tn = tlo1 + (thi1 - tlo1) * ((float)(clo1 - KK_) / (float)(clo1 - chi1));
                } else {
                    const float z    = (t1 - mu1) / sg1;
                    const float dens = fmaxf(408.5f * __expf(-0.5f * z * z) / sg1, 1.f);
                    tn = t1 + (float)(c1 - KK_) / dens;
                }
                if (hlo1 && !(tn > tlo1)) tn = hhi1 ? 0.5f * (tlo1 + thi1) : tlo1 + 0.25f * sg1;
                if (hhi1 && !(tn < thi1)) tn = hlo1 ? 0.5f * (tlo1 + thi1) : thi1 - 0.25f * sg1;
                t1 = tn;
            }
        }
    }
    if (!done0) res0 = bisect_exact(key0, hlo0, hhi0, tlo0, thi0);
    if (!done1) res1 = bisect_exact(key1, hlo1, hhi1, tlo1, thi1);
    out0 = res0;
    out1 = res1;
}
// load 8 contiguous f32, emit hi/lo bf16 fragments
__device__ __forceinline__ void split8(const float* __restrict__ src,
                                       bf16x8& h8, bf16x8& l8) {
    float4 a = *(const float4*)src;
    float4 b = *(const float4*)(src + 4);
    float v[8] = {a.x, a.y, a.z, a.w, b.x, b.y, b.z, b.w};
#pragma unroll
    for (int i = 0; i < 8; ++i) {
        ushort_t hb = bf16_rne(v[i]);
        h8[i] = (short)hb;
        l8[i] = (short)bf16_rne(v[i] - bf16_f(hb));
    }
}

// ---- shared device bodies -------------------------------------------------
__device__ __forceinline__ void prep_tile_body(int wb,
                                               const float* __restrict__ Wq,
                                               const float* __restrict__ Wo,
                                               ushort_t* __restrict__ WqTh,
                                               ushort_t* __restrict__ WqTl,
                                               ushort_t* __restrict__ WoTh,
                                               ushort_t* __restrict__ WoTl,
                                               float (*tile)[33]) {
    const int bx = wb & 63, by = wb >> 6;
    const bool isQ = bx < 48;
    const int  nb  = (isQ ? bx : bx - 48) * 32;
    const int  kb  = by * 32;
    const int  Nn  = isQ ? TRIPLE_ : DIM_;
    const float* W = isQ ? Wq : Wo;
    ushort_t* Th   = isQ ? WqTh : WoTh;
    ushort_t* Tl   = isQ ? WqTl : WoTl;
    const int tx = threadIdx.x & 31, ty = threadIdx.x >> 5;   // ty 0..7
    for (int yy = ty; yy < 32; yy += 8)
        tile[yy][tx] = W[(size_t)(kb + yy) * Nn + nb + tx];
    __syncthreads();
    for (int yy = ty; yy < 32; yy += 8) {
        float v = tile[tx][yy];
        ushort_t hb = bf16_rne(v);
        size_t idx = (size_t)(nb + yy) * DIM_ + kb + tx;
        Th[idx] = hb;
        Tl[idx] = bf16_rne(v - bf16_f(hb));
    }
}

__device__ __forceinline__ void qkv_tile_body(
    int n0, int m0blk,
    const float* __restrict__ X,
    const ushort_t* __restrict__ Wh, const ushort_t* __restrict__ Wl,
    ushort_t* __restrict__ Qh, ushort_t* __restrict__ Ql,
    ushort_t* __restrict__ Kh, ushort_t* __restrict__ Kl,
    ushort_t* __restrict__ Vt,
    ushort_t (*stile)[4608], ushort_t (*BshH)[2048], ushort_t (*BshL)[2048]) {
    const int t = threadIdx.x, w = t >> 6, l = t & 63;
    const int ln = l & 15, quad = l >> 4;
    const int m0 = m0blk * 128 + w * 32;
    f32x4 acc[2][4] = {};
    {
        const size_t xrow0 = (size_t)(m0 + ln) * DIM_;
        const size_t xrow1 = (size_t)(m0 + 16 + ln) * DIM_;
        const int srow = t >> 2;            // 0..63  (staging row)
        const int sk   = (t & 3) << 3;      // 0,8,16,24
        const size_t gb = (size_t)(n0 + srow) * DIM_ + sk;
        us8 nh = *(const us8*)&Wh[gb];
        us8 nl = *(const us8*)&Wl[gb];
        *(us8*)&BshH[0][t * 8] = nh;
        *(us8*)&BshL[0][t * 8] = nl;
        int cur = 0;
        for (int k0 = 0; k0 < DIM_; k0 += 32) {
            const bool more = (k0 + 32) < DIM_;
            const size_t gnext = gb + (size_t)(more ? k0 + 32 : 0);
            nh = *(const us8*)&Wh[gnext];           // issue BEFORE barrier
            nl = *(const us8*)&Wl[gnext];
            __syncthreads();                        // buf[cur] ready
            const int ko = k0 + quad * 8;
            bf16x8 ah0, al0, ah1, al1;
            split8(&X[xrow0 + ko], ah0, al0);
            split8(&X[xrow1 + ko], ah1, al1);
#pragma unroll
            for (int j = 0; j < 4; ++j) {
                const int slot = (((j << 4) + ln) << 5) + (quad << 3);
                bf16x8 bh = *(const bf16x8*)&BshH[cur][slot];
                bf16x8 bl = *(const bf16x8*)&BshL[cur][slot];
                acc[0][j] = __builtin_amdgcn_mfma_f32_16x16x32_bf16(ah0, bh, acc[0][j], 0, 0, 0);
                acc[0][j] = __builtin_amdgcn_mfma_f32_16x16x32_bf16(al0, bh, acc[0][j], 0, 0, 0);
                acc[0][j] = __builtin_amdgcn_mfma_f32_16x16x32_bf16(ah0, bl, acc[0][j], 0, 0, 0);
                acc[1][j] = __builtin_amdgcn_mfma_f32_16x16x32_bf16(ah1, bh, acc[1][j], 0, 0, 0);
                acc[1][j] = __builtin_amdgcn_mfma_f32_16x16x32_bf16(al1, bh, acc[1][j], 0, 0, 0);
                acc[1][j] = __builtin_amdgcn_mfma_f32_16x16x32_bf16(ah1, bl, acc[1][j], 0, 0, 0);
            }
            if (more) {
                *(us8*)&BshH[cur ^ 1][t * 8] = nh;
                *(us8*)&BshL[cur ^ 1][t * 8] = nl;
            }
            cur ^= 1;
        }
    }
    const int sec = n0 >> 9;           // block-uniform
    const int h   = (n0 >> 6) & 7;
    ushort_t* tw  = stile[w];
    const int b = m0 >> 10, nnb = m0 & 1023;
    if (sec < 2) {
        ushort_t* Hp = sec ? Kh : Qh;
        ushort_t* Lp = sec ? Kl : Ql;
        const float qsc = sec ? 1.0f : SCALE_;   // fold attention scale into Q
#pragma unroll
        for (int i = 0; i < 2; ++i)
#pragma unroll
            for (int j = 0; j < 4; ++j)
#pragma unroll
                for (int g = 0; g < 4; ++g) {
                    const float v = acc[i][j][g] * qsc;
                    const ushort_t hb = bf16_rne(v);
                    const ushort_t lb = bf16_rne(v - bf16_f(hb));
                    const int tok = i * 16 + quad * 4 + g;
                    const int d   = j * 16 + ln;
                    tw[tok * 72 + d]        = hb;
                    tw[2304 + tok * 72 + d] = lb;
                }
        __syncthreads();
        const size_t rowbase = ((size_t)(b * 8 + h) * 1024 + nnb) * 64;
        const int dd = (l & 7) * 8;
#pragma unroll
        for (int s = 0; s < 4; ++s) {
            const int tl = s * 8 + (l >> 3);
            const size_t off = rowbase + (size_t)tl * 64 + dd;
            *(us8*)&Hp[off] = *(const us8*)&tw[tl * 72 + dd];
            *(us8*)&Lp[off] = *(const us8*)&tw[2304 + tl * 72 + dd];
        }
    } else {
#pragma unroll
        for (int i = 0; i < 2; ++i)
#pragma unroll
            for (int j = 0; j < 4; ++j)
#pragma unroll
                for (int g = 0; g < 4; ++g)
                    tw[(j * 16 + ln) * 40 + i * 16 + quad * 4 + g] = bf16_rne(acc[i][j][g]);
        __syncthreads();
        const size_t vbase = (size_t)(b * 8 + h) * 65536 + nnb;
#pragma unroll
        for (int p = 0; p < 2; ++p) {
            const int d = (p << 5) + (l >> 1);
            const int c = (l & 1) << 4;
            ushort_t* dst = &Vt[vbase + (size_t)d * 1024 + c];
            *(us8*)dst       = *(const us8*)&tw[d * 40 + c];
            *(us8*)(dst + 8) = *(const us8*)&tw[d * 40 + c + 8];
        }
    }
}

// ---------------------------------------------------------------------------
// Standalone prep (fallback path; weights only)
// ---------------------------------------------------------------------------
__global__ __launch_bounds__(256) void prep_split(const float* __restrict__ Wq,
                                                  const float* __restrict__ Wo,
                                                  ushort_t* __restrict__ WqTh,
                                                  ushort_t* __restrict__ WqTl,
                                                  ushort_t* __restrict__ WoTh,
                                                  ushort_t* __restrict__ WoTl) {
    __shared__ float tile[32][33];
    prep_tile_body(blockIdx.x, Wq, Wo, WqTh, WqTl, WoTh, WoTl, tile);
}

// ---------------------------------------------------------------------------
// Standalone qkv GEMM (fallback path; round-13 proven)
// ---------------------------------------------------------------------------
__global__ __launch_bounds__(256) void gemm_qkv_mfma(
    const float* __restrict__ X,
    const ushort_t* __restrict__ Wh, const ushort_t* __restrict__ Wl,
    ushort_t* __restrict__ Qh, ushort_t* __restrict__ Ql,
    ushort_t* __restrict__ Kh, ushort_t* __restrict__ Kl,
    ushort_t* __restrict__ Vt) {
    __shared__ ushort_t stile[4][4608];
    __shared__ ushort_t BshH[2][2048];
    __shared__ ushort_t BshL[2][2048];
    qkv_tile_body(blockIdx.y * 64, blockIdx.x, X, Wh, Wl,
                  Qh, Ql, Kh, Kl, Vt, stile, BshH, BshL);
}

// ---------------------------------------------------------------------------
// Fused prep + qkv (cooperative; 512 blocks = 2 WG/CU guaranteed resident:
// 2 x 52 KB LDS = 104 KB <= 160 KB). Phase 1 grid-strides 1024 weight
// tiles; grid.sync (+fence); phase 2 grid-strides 768 qkv tiles. Removes
// one kernel boundary (~9 us measured in round 10).
// ---------------------------------------------------------------------------
__global__ __launch_bounds__(256) void fused_prep_qkv(
    const float* __restrict__ X,
    const float* __restrict__ Wq, const float* __restrict__ Wo,
    ushort_t* __restrict__ WqTh, ushort_t* __restrict__ WqTl,
    ushort_t* __restrict__ WoTh, ushort_t* __restrict__ WoTl,
    ushort_t* __restrict__ Qh, ushort_t* __restrict__ Ql,
    ushort_t* __restrict__ Kh, ushort_t* __restrict__ Kl,
    ushort_t* __restrict__ Vt) {
    __shared__ ushort_t stile[4][4608];   // 36 KB (phase 1 reuses as tile)
    __shared__ ushort_t BshH[2][2048];
    __shared__ ushort_t BshL[2][2048];

    {
        float (*tile)[33] = (float(*)[33])&stile[0][0];   // 4224 B < 36 KB
        for (int vb = blockIdx.x; vb < 1024; vb += gridDim.x) {
            prep_tile_body(vb, Wq, Wo, WqTh, WqTl, WoTh, WoTl, tile);
            __syncthreads();              // tile reuse across iterations
        }
    }
    __threadfence();                      // device-scope visibility
    cg::this_grid().sync();

    for (int vb = blockIdx.x; vb < 768; vb += gridDim.x) {
        qkv_tile_body((vb >> 5) * 64, vb & 31, X, WqTh, WqTl,
                      Qh, Ql, Kh, Kl, Vt, stile, BshH, BshL);
        __syncthreads();
    }
}

// ---------------------------------------------------------------------------
// out-proj (round-12 win): 64x64 tile, grid (64,8) = 512 WGs = 2 WG/CU =
// 8 waves/CU. Each wave owns 16 rows (acc[4], 12 MFMAs/k-step).
// ---------------------------------------------------------------------------
__global__ __launch_bounds__(256) void gemm_out_mfma(
    const ushort_t* __restrict__ Ah, const ushort_t* __restrict__ Al,
    const ushort_t* __restrict__ Wh, const ushort_t* __restrict__ Wl,
    const float* __restrict__ bias, float* __restrict__ C) {
    __shared__ ushort_t BshH[2][2048];
    __shared__ ushort_t BshL[2][2048];
    const int t = threadIdx.x, w = t >> 6, l = t & 63;
    const int ln = l & 15, quad = l >> 4;
    const int n0 = blockIdx.y * 64;
    const int m0 = blockIdx.x * 64 + w * 16;
    f32x4 acc[4] = {};
    {
        const size_t arow0 = (size_t)(m0 + ln) * INNER_;
        const int srow = t >> 2;
        const int sk   = (t & 3) << 3;
        const size_t gb = (size_t)(n0 + srow) * INNER_ + sk;
        us8 nh = *(const us8*)&Wh[gb];
        us8 nl = *(const us8*)&Wl[gb];
        *(us8*)&BshH[0][t * 8] = nh;
        *(us8*)&BshL[0][t * 8] = nl;
        int cur = 0;
        for (int k0 = 0; k0 < INNER_; k0 += 32) {
            const bool more = (k0 + 32) < INNER_;
            const size_t gnext = gb + (size_t)(more ? k0 + 32 : 0);
            nh = *(const us8*)&Wh[gnext];
            nl = *(const us8*)&Wl[gnext];
            __syncthreads();
            const int ko = k0 + quad * 8;
            bf16x8 ah0 = *(const bf16x8*)&Ah[arow0 + ko];
            bf16x8 al0 = *(const bf16x8*)&Al[arow0 + ko];
#pragma unroll
            for (int j = 0; j < 4; ++j) {
                const int slot = (((j << 4) + ln) << 5) + (quad << 3);
                bf16x8 bh = *(const bf16x8*)&BshH[cur][slot];
                bf16x8 bl = *(const bf16x8*)&BshL[cur][slot];
                acc[j] = __builtin_amdgcn_mfma_f32_16x16x32_bf16(ah0, bh, acc[j], 0, 0, 0);
                acc[j] = __builtin_amdgcn_mfma_f32_16x16x32_bf16(al0, bh, acc[j], 0, 0, 0);
                acc[j] = __builtin_amdgcn_mfma_f32_16x16x32_bf16(ah0, bl, acc[j], 0, 0, 0);
            }
            if (more) {
                *(us8*)&BshH[cur ^ 1][t * 8] = nh;
                *(us8*)&BshL[cur ^ 1][t * 8] = nl;
            }
            cur ^= 1;
        }
    }
#pragma unroll
    for (int j = 0; j < 4; ++j) {
        const int col = n0 + j * 16 + ln;
        const float bb = bias[col];
#pragma unroll
        for (int g = 0; g < 4; ++g) {
            const int token = m0 + quad * 4 + g;
            C[(size_t)token * DIM_ + col] = acc[j][g] + bb;
        }
    }
}

// ---------------------------------------------------------------------------
// MFMA kNN attention (frozen round-4 state, single 2048-WG launch).
// ---------------------------------------------------------------------------
__global__ __launch_bounds__(512)
__attribute__((amdgpu_waves_per_eu(4, 4)))
void attn_mfma(const ushort_t* __restrict__ Qh,
               const ushort_t* __restrict__ Ql,
               const ushort_t* __restrict__ Kh,
               const ushort_t* __restrict__ Kl,
               const ushort_t* __restrict__ Vt,
               ushort_t* __restrict__ Oh,
               ushort_t* __restrict__ Ol) {
    __shared__ float sdots[16 * 1024];        // 64 KB
    __shared__ float spartial[4][16][17];     // 4.25 KB j-split merge buffer

    const int t    = threadIdx.x;
    const int w    = t >> 6;        // wave 0..7
    const int l    = t & 63;
    const int ln   = l & 15;
    const int quad = l >> 4;
    const int wg   = blockIdx.x;
    const int bh   = wg & 31;       // XCD-local heads
    const int i0   = (wg >> 5) << 4;

    const size_t bhoff = (size_t)bh << 16;

    // ---- Q fragments (same for all waves; already scaled by 2^-3)
    const ushort_t* qp  = Qh + bhoff + (size_t)(i0 + ln) * 64 + (quad << 3);
    const ushort_t* qlp = Ql + bhoff + (size_t)(i0 + ln) * 64 + (quad << 3);
    bf16x8 qh0 = *(const bf16x8*)qp;
    bf16x8 qh1 = *(const bf16x8*)(qp + 32);
    bf16x8 ql0 = *(const bf16x8*)qlp;
    bf16x8 ql1 = *(const bf16x8*)(qlp + 32);

    // ---- phase-3 V base, computed early for the in-phase-2 prefetch
    const int dblk  = w & 3;
    const int jbase = (w & 4) << 7;   // 0 or 512
    const ushort_t* vp =
        Vt + bhoff + (size_t)((dblk << 4) + ln) * 1024 + (quad << 3) + jbase;
    bf16x8 vpre[8];

    // ---- Phase 1: dots. wave w covers j in [w*128, w*128+128)
    for (int tt = 0; tt < 8; ++tt) {
        const int j0 = ((w << 3) + tt) << 4;
        const ushort_t* kp  = Kh + bhoff + (size_t)(j0 + ln) * 64 + (quad << 3);
        const ushort_t* klp = Kl + bhoff + (size_t)(j0 + ln) * 64 + (quad << 3);
        bf16x8 kh0 = *(const bf16x8*)kp;
        bf16x8 kh1 = *(const bf16x8*)(kp + 32);
        bf16x8 kl0 = *(const bf16x8*)klp;
        bf16x8 kl1 = *(const bf16x8*)(klp + 32);
        f32x4 acc = {0.f, 0.f, 0.f, 0.f};
        acc = __builtin_amdgcn_mfma_f32_16x16x32_bf16(qh0, kh0, acc, 0, 0, 0);
        acc = __builtin_amdgcn_mfma_f32_16x16x32_bf16(qh1, kh1, acc, 0, 0, 0);
        acc = __builtin_amdgcn_mfma_f32_16x16x32_bf16(qh0, kl0, acc, 0, 0, 0);
        acc = __builtin_amdgcn_mfma_f32_16x16x32_bf16(qh1, kl1, acc, 0, 0, 0);
        acc = __builtin_amdgcn_mfma_f32_16x16x32_bf16(ql0, kh0, acc, 0, 0, 0);
        acc = __builtin_amdgcn_mfma_f32_16x16x32_bf16(ql1, kh1, acc, 0, 0, 0);
#pragma unroll
        for (int g = 0; g < 4; ++g) {
            const int row = (quad << 2) + g;
            sdots[(row << 10) + ((j0 + ln) ^ ((row & 7) << 2))] = acc[g];
        }
    }
    __syncthreads();

    // ---- Phase 2: fused 2-row top-k + softmax + in-place bf16 P
    ushort_t* sP = (ushort_t*)sdots;
    {
        const int r0 = w << 1, r1 = r0 | 1;
        const int swz0 = (r0 & 7) << 2, swz1 = (r1 & 7) << 2;
        const float* s0 = &sdots[r0 << 10];
        const float* s1 = &sdots[r1 << 10];
        // lane l holds keys for j = 4l + 256m + i  (m=0..3, i=0..3)
        unsigned key0[16], key1[16];
        float sa0 = 0.f, sb0 = 0.f, sa1 = 0.f, sb1 = 0.f;
#pragma unroll
        for (int m = 0; m < 4; ++m) {
            f32x4 kv0 = *(const f32x4*)&s0[((l << 2) + (m << 8)) ^ swz0];
            f32x4 kv1 = *(const f32x4*)&s1[((l << 2) + (m << 8)) ^ swz1];
#pragma unroll
            for (int i = 0; i < 4; ++i) {
                key0[(m << 2) + i] = f2key(kv0[i]);
                key1[(m << 2) + i] = f2key(kv1[i]);
                sa0 += kv0[i];
                sb0 += kv0[i] * kv0[i];
                sa1 += kv1[i];
                sb1 += kv1[i] * kv1[i];
            }
        }
        // 4 independent reduction chains in one loop (latency overlap)
#pragma unroll
        for (int off = 32; off; off >>= 1) {
            sa0 += __shfl_xor(sa0, off, 64);
            sb0 += __shfl_xor(sb0, off, 64);
            sa1 += __shfl_xor(sa1, off, 64);
            sb1 += __shfl_xor(sb1, off, 64);
        }
        const float mu0 = sa0 * (1.0f / 1024.f);
        const float sg0 = sqrtf(fmaxf(sb0 * (1.0f / 1024.f) - mu0 * mu0, 1e-20f));
        const float mu1 = sa1 * (1.0f / 1024.f);
        const float sg1 = sqrtf(fmaxf(sb1 * (1.0f / 1024.f) - mu1 * mu1, 1e-20f));

        unsigned res0, res1;
        topk2(key0, key1, mu0, sg0, mu1, sg1, res0, res1);

        const float thr0 = key2f(res0), thr1 = key2f(res1);
        float pv0[16], pv1[16];
        float ls0 = 0.f, ls1 = 0.f;
#pragma unroll
        for (int m = 0; m < 16; ++m) {
            float p0 = (key0[m] >= res0) ? __expf(key2f(key0[m]) - thr0) : 0.f;
            float p1 = (key1[m] >= res1) ? __expf(key2f(key1[m]) - thr1) : 0.f;
            pv0[m] = p0;
            pv1[m] = p1;
            ls0 += p0;
            ls1 += p1;
        }
        // ---- prefetch first half of phase-3 V tiles NOW: keys are dead,
        // loads fly during the ls-reduce shuffles + P pack + barrier wait
#pragma unroll
        for (int p = 0; p < 8; ++p)
            vpre[p] = *(const bf16x8*)(vp + p * 32);
#pragma unroll
        for (int off = 32; off; off >>= 1) {
            ls0 += __shfl_xor(ls0, off, 64);
            ls1 += __shfl_xor(ls1, off, 64);
        }
        const float inv0 = 1.f / ls0, inv1 = 1.f / ls1;
        // store P (bf16, phase-3 layout): j = 4l + 256m + i
#pragma unroll
        for (int m = 0; m < 4; ++m) {
            const int g0 = ((l >> 1) + (m << 5)) ^ (r0 & 7);
            const int g1 = ((l >> 1) + (m << 5)) ^ (r1 & 7);
            ushort4 pk0 = make_ushort4(bf16_rne(pv0[(m << 2) + 0] * inv0),
                                       bf16_rne(pv0[(m << 2) + 1] * inv0),
                                       bf16_rne(pv0[(m << 2) + 2] * inv0),
                                       bf16_rne(pv0[(m << 2) + 3] * inv0));
            ushort4 pk1 = make_ushort4(bf16_rne(pv1[(m << 2) + 0] * inv1),
                                       bf16_rne(pv1[(m << 2) + 1] * inv1),
                                       bf16_rne(pv1[(m << 2) + 2] * inv1),
                                       bf16_rne(pv1[(m << 2) + 3] * inv1));
            *(ushort4*)&sP[(r0 << 11) + (g0 << 3) + ((l & 1) << 2)] = pk0;
            *(ushort4*)&sP[(r1 << 11) + (g1 << 3) + ((l & 1) << 2)] = pk1;
        }
    }
    __syncthreads();

    // ---- Phase 3: O = P @ V.  wave w: d-block (w&3), j-half (w&4 ? hi : lo)
    const int prow = ln << 11;
    const int rsw  = ln & 7;
    // issue second-half V loads, overlapped with the first 8 MFMAs
    bf16x8 vnx[8];
#pragma unroll
    for (int p = 0; p < 8; ++p)
        vnx[p] = *(const bf16x8*)(vp + 256 + p * 32);
    f32x4 oa[4] = {};
    __builtin_amdgcn_s_setprio(1);
#pragma unroll
    for (int p = 0; p < 8; ++p) {
        const int j0 = p * 32;
        const int g = ((jbase + j0) >> 3) + quad;
        bf16x8 af = *(const bf16x8*)&sP[prow + ((g ^ rsw) << 3)];
        oa[p & 3] = __builtin_amdgcn_mfma_f32_16x16x32_bf16(af, vpre[p], oa[p & 3], 0, 0, 0);
    }
#pragma unroll
    for (int p = 0; p < 8; ++p) {
        const int j0 = 256 + p * 32;
        const int g = ((jbase + j0) >> 3) + quad;
        bf16x8 af = *(const bf16x8*)&sP[prow + ((g ^ rsw) << 3)];
        oa[p & 3] = __builtin_amdgcn_mfma_f32_16x16x32_bf16(af, vnx[p], oa[p & 3], 0, 0, 0);
    }
    __builtin_amdgcn_s_setprio(0);
    f32x4 oacc = (oa[0] + oa[1]) + (oa[2] + oa[3]);

    if (w & 4) {
#pragma unroll
        for (int g = 0; g < 4; ++g)
            spartial[dblk][(quad << 2) + g][ln] = oacc[g];
    }
    __syncthreads();
    if (!(w & 4)) {
        const int b = bh >> 3, h = bh & 7;
        const size_t obase =
            ((size_t)(b << 10) + i0 + (quad << 2)) * 512 + (h << 6) + (dblk << 4) + ln;
#pragma unroll
        for (int g = 0; g < 4; ++g) {
            const float v = oacc[g] + spartial[dblk][(quad << 2) + g][ln];
            ushort_t hb = bf16_rne(v);
            Oh[obase + (size_t)g * 512] = hb;
            Ol[obase + (size_t)g * 512] = bf16_rne(v - bf16_f(hb));
        }
    }
}

extern "C" void kernel_launch(void* const* d_in, const int* in_sizes, int n_in,
                              void* d_out, int out_size, void* d_ws, size_t ws_size,
                              hipStream_t stream) {
    const float* x     = (const float*)d_in[0];
    const float* w_qkv = (const float*)d_in[1];
    const float* w_out = (const float*)d_in[2];
    const float* b_out = (const float*)d_in[3];
    float*       out   = (float*)d_out;

    const size_t ON  = (size_t)4096 * 512;
    const size_t WQT = (size_t)1536 * 512;
    const size_t WOT = (size_t)512 * 512;
    const size_t QK  = (size_t)32 * 1024 * 64;

    ushort_t* p    = (ushort_t*)d_ws;
    ushort_t* Oh   = p;            p += ON;
    ushort_t* Ol   = p;            p += ON;
    ushort_t* WqTh = p;            p += WQT;
    ushort_t* WqTl = p;            p += WQT;
    ushort_t* WoTh = p;            p += WOT;
    ushort_t* WoTl = p;            p += WOT;
    ushort_t* Qh   = p;            p += QK;
    ushort_t* Ql   = p;            p += QK;
    ushort_t* Kh   = p;            p += QK;
    ushort_t* Kl   = p;            p += QK;
    ushort_t* Vt   = p;            p += QK;   // total exactly 32 MiB

    // ---- prep + qkv: cooperative fusion (512 blocks = 2 WG/CU, safely
    // co-resident); on ANY launch error fall back to the proven separate
    // launches so correctness cannot regress.
    void* args[] = {(void*)&x, (void*)&w_qkv, (void*)&w_out,
                    (void*)&WqTh, (void*)&WqTl, (void*)&WoTh, (void*)&WoTl,
                    (void*)&Qh, (void*)&Ql, (void*)&Kh, (void*)&Kl, (void*)&Vt};
    hipError_t ce = hipLaunchCooperativeKernel((void*)fused_prep_qkv,
                                               dim3(512), dim3(256),
                                               args, 0, stream);
    if (ce != hipSuccess) {
        prep_split<<<dim3(1024), 256, 0, stream>>>(w_qkv, w_out, WqTh, WqTl,
                                                   WoTh, WoTl);
        gemm_qkv_mfma<<<dim3(4096 / 128, TRIPLE_ / 64), 256, 0, stream>>>(
            x, WqTh, WqTl, Qh, Ql, Kh, Kl, Vt);
    }

    attn_mfma<<<dim3(B_ * H_ * (N_ / 16)), 512, 0, stream>>>(Qh, Ql, Kh, Kl,
                                                             Vt, Oh, Ol);

    gemm_out_mfma<<<dim3(4096 / 64, DIM_ / 64), 256, 0, stream>>>(
        Oh, Ol, WoTh, WoTl, b_out, out);
}

// Round 15
// 225.546 us; speedup vs baseline: 1.3950x; 1.3950x over previous
//
#include <hip/hip_runtime.h>
#include <cstddef>

#define B_      4
#define N_      1024
#define DIM_    512
#define H_      8
#define D_      64
#define INNER_  512
#define TRIPLE_ 1536
#define KK_     716        // int(1024 * 0.7)
#define SCALE_  0.125f     // 64^-0.5

typedef short bf16x8 __attribute__((ext_vector_type(8)));
typedef float f32x4  __attribute__((ext_vector_type(4)));
typedef unsigned short ushort_t;
typedef ushort_t us8 __attribute__((ext_vector_type(8)));

__device__ __forceinline__ unsigned short bf16_rne(float f) {
    unsigned u = __float_as_uint(f);
    return (unsigned short)((u + 0x7FFFu + ((u >> 16) & 1u)) >> 16);
}
__device__ __forceinline__ float bf16_f(unsigned short s) {
    return __uint_as_float((unsigned)s << 16);
}
// order-preserving float->uint key (descending float == descending uint)
__device__ __forceinline__ unsigned f2key(float f) {
    unsigned u = __float_as_uint(f);
    return u ^ ((u & 0x80000000u) ? 0xFFFFFFFFu : 0x80000000u);
}
__device__ __forceinline__ float key2f(unsigned k) {
    unsigned u = (k & 0x80000000u) ? (k ^ 0x80000000u) : ~k;
    return __uint_as_float(u);
}
// wave-wide count of per-lane tallies lc in [0,16] via 5 bit-plane ballots
__device__ __forceinline__ int wave_count(int lc) {
    int c = __popcll(__ballot(lc & 1));
    c += __popcll(__ballot(lc & 2)) << 1;
    c += __popcll(__ballot(lc & 4)) << 2;
    c += __popcll(__ballot(lc & 8)) << 3;
    c += __popcll(__ballot(lc & 16)) << 4;
    return c;
}
__device__ __forceinline__ int count_ge(const unsigned* key, unsigned kt) {
    int lc = 0;
#pragma unroll
    for (int m = 0; m < 16; ++m) lc += (key[m] >= kt) ? 1 : 0;
    return wave_count(lc);
}
// guaranteed-exact uint bisection fallback (rare path)
__device__ __forceinline__ unsigned bisect_exact(const unsigned* key,
                                                 bool hlo, bool hhi,
                                                 float tlo, float thi) {
    unsigned klo = hlo ? f2key(tlo) : 0u;
    unsigned khi = hhi ? f2key(thi) : 0xFFFFFFFFu;
    while (khi - klo > 1u) {
        const unsigned km = klo + ((khi - klo) >> 1);
        const int c = count_ge(key, km);
        if (c >= KK_) { klo = km; if (c == KK_) break; }
        else khi = km;
    }
    return klo;
}
// dual-row interpolation-seeded secant search, chains interleaved for latency
__device__ __forceinline__ void topk2(const unsigned* key0, const unsigned* key1,
                                      float mu0, float sg0, float mu1, float sg1,
                                      unsigned& out0, unsigned& out1) {
    bool done0 = false, done1 = false;
    float tlo0 = 0.f, thi0 = 0.f, tlo1 = 0.f, thi1 = 0.f;
    int   clo0 = 0,   chi0 = 0,   clo1 = 0,   chi1 = 0;
    bool  hlo0 = false, hhi0 = false, hlo1 = false, hhi1 = false;
    float t0 = mu0 - 0.52189f * sg0;      // seed at the 716/1024 quantile
    float t1 = mu1 - 0.52189f * sg1;
    unsigned res0 = 0u, res1 = 0u;
    for (int it = 0; it < 10; ++it) {
        if (done0 & done1) break;
        const unsigned kt0 = f2key(t0);
        const unsigned kt1 = f2key(t1);
        int lc0 = 0, lc1 = 0;
#pragma unroll
        for (int m = 0; m < 16; ++m) {
            lc0 += (key0[m] >= kt0) ? 1 : 0;
            lc1 += (key1[m] >= kt1) ? 1 : 0;
        }
        const int c0 = wave_count(lc0);
        const int c1 = wave_count(lc1);
        if (!done0) {
            if (c0 == KK_) { res0 = kt0; done0 = true; }
            else {
                if (c0 > KK_) { tlo0 = t0; clo0 = c0; hlo0 = true; }
                else          { thi0 = t0; chi0 = c0; hhi0 = true; }
                float tn;
                if (hlo0 && hhi0) {
                    tn = tlo0 + (thi0 - tlo0) * ((float)(clo0 - KK_) / (float)(clo0 - chi0));
                } else {
                    const float z    = (t0 - mu0) / sg0;
                    const float dens = fmaxf(408.5f * __expf(-0.5f * z * z) / sg0, 1.f);
                    tn = t0 + (float)(c0 - KK_) / dens;
                }
                if (hlo0 && !(tn > tlo0)) tn = hhi0 ? 0.5f * (tlo0 + thi0) : tlo0 + 0.25f * sg0;
                if (hhi0 && !(tn < thi0)) tn = hlo0 ? 0.5f * (tlo0 + thi0) : thi0 - 0.25f * sg0;
                t0 = tn;
            }
        }
        if (!done1) {
            if (c1 == KK_) { res1 = kt1; done1 = true; }
            else {
                if (c1 > KK_) { tlo1 = t1; clo1 = c1; hlo1 = true; }
                else          { thi1 = t1; chi1 = c1; hhi1 = true; }
                float tn;
                if (hlo1 && hhi1) {
                    tn = tlo1 + (thi1 - tlo1) * ((float)(clo1 - KK_) / (float)(clo1 - chi1));
                } else {
                    const float z    = (t1 - mu1) / sg1;
                    const float dens = fmaxf(408.5f * __expf(-0.5f * z * z) / sg1, 1.f);
                    tn = t1 + (float)(c1 - KK_) / dens;
                }
                if (hlo1 && !(tn > tlo1)) tn = hhi1 ? 0.5f * (tlo1 + thi1) : tlo1 + 0.25f * sg1;
                if (hhi1 && !(tn < thi1)) tn = hlo1 ? 0.5f * (tlo1 + thi1) : thi1 - 0.25f * sg1;
                t1 = tn;
            }
        }
    }
    if (!done0) res0 = bisect_exact(key0, hlo0, hhi0, tlo0, thi0);
    if (!done1) res1 = bisect_exact(key1, hlo1, hhi1, tlo1, thi1);
    out0 = res0;
    out1 = res1;
}
// split 8 fp32 (contiguous) into hi/lo bf16 fragments
__device__ __forceinline__ void split8(const float* __restrict__ src,
                                       bf16x8& h8, bf16x8& l8) {
    float4 a = *(const float4*)src;
    float4 b = *(const float4*)(src + 4);
    float v[8] = {a.x, a.y, a.z, a.w, b.x, b.y, b.z, b.w};
#pragma unroll
    for (int i = 0; i < 8; ++i) {
        ushort_t hb = bf16_rne(v[i]);
        h8[i] = (short)hb;
        l8[i] = (short)bf16_rne(v[i] - bf16_f(hb));
    }
}
// split 8 fp32 (already in regs) into hi/lo bf16 fragments
__device__ __forceinline__ void cvt8(const float* v, bf16x8& h8, bf16x8& l8) {
#pragma unroll
    for (int i = 0; i < 8; ++i) {
        ushort_t hb = bf16_rne(v[i]);
        h8[i] = (short)hb;
        l8[i] = (short)bf16_rne(v[i] - bf16_f(hb));
    }
}

// ---------------------------------------------------------------------------
// qkv GEMM, round 15: B staged DIRECTLY from fp32 w_qkv (in-staging
// transpose+split; weights are 3 MB -> L2-resident, split VALU proven
// non-binding in rounds 7/13). The LDS image is byte-identical to the old
// WqT path -> bitwise-identical output. This deletes the prep kernel and
// one launch boundary (~9 us measured in round 10). 128x64 tile, 768
// blocks = 3 blocks/CU. Q epilogue pre-folds SCALE (2^-3, exact in bf16).
// w_qkv layout: [DIM_ k][TRIPLE_ n] row-major; B^T[n][k] = Wq[k*TRIPLE_+n].
// ---------------------------------------------------------------------------
__global__ __launch_bounds__(256) void gemm_qkv_mfma(
    const float* __restrict__ X,
    const float* __restrict__ Wq,
    ushort_t* __restrict__ Qh, ushort_t* __restrict__ Ql,
    ushort_t* __restrict__ Kh, ushort_t* __restrict__ Kl,
    ushort_t* __restrict__ Vt) {
    __shared__ ushort_t stile[4][4608];   // 36 KB epilogue scratch
    __shared__ ushort_t BshH[2][2048];    // 8 KB x2 double buffer
    __shared__ ushort_t BshL[2][2048];
    const int t = threadIdx.x, w = t >> 6, l = t & 63;
    const int ln = l & 15, quad = l >> 4;
    const int n0 = blockIdx.y * 64;
    const int m0 = blockIdx.x * 128 + w * 32;
    f32x4 acc[2][4] = {};
    {
        const size_t xrow0 = (size_t)(m0 + ln) * DIM_;
        const size_t xrow1 = (size_t)(m0 + 16 + ln) * DIM_;
        const int srow = t >> 2;            // 0..63  (staging row = n offset)
        const int sk   = (t & 3) << 3;      // 0,8,16,24 (k offset)
        const int gn   = n0 + srow;         // global B column
        float nv[8];
#pragma unroll
        for (int i = 0; i < 8; ++i)         // prologue: k0 = 0 panel
            nv[i] = Wq[(size_t)(sk + i) * TRIPLE_ + gn];
        {
            bf16x8 h8, l8;
            cvt8(nv, h8, l8);
            *(bf16x8*)&BshH[0][t * 8] = h8;
            *(bf16x8*)&BshL[0][t * 8] = l8;
        }
        int cur = 0;
        for (int k0 = 0; k0 < DIM_; k0 += 32) {
            const bool more = (k0 + 32) < DIM_;
            if (more) {                      // issue next panel BEFORE barrier
#pragma unroll
                for (int i = 0; i < 8; ++i)
                    nv[i] = Wq[(size_t)(k0 + 32 + sk + i) * TRIPLE_ + gn];
            }
            __syncthreads();                 // buf[cur] ready
            const int ko = k0 + quad * 8;
            bf16x8 ah0, al0, ah1, al1;
            split8(&X[xrow0 + ko], ah0, al0);
            split8(&X[xrow1 + ko], ah1, al1);
#pragma unroll
            for (int j = 0; j < 4; ++j) {
                const int slot = (((j << 4) + ln) << 5) + (quad << 3);
                bf16x8 bh = *(const bf16x8*)&BshH[cur][slot];
                bf16x8 bl = *(const bf16x8*)&BshL[cur][slot];
                acc[0][j] = __builtin_amdgcn_mfma_f32_16x16x32_bf16(ah0, bh, acc[0][j], 0, 0, 0);
                acc[0][j] = __builtin_amdgcn_mfma_f32_16x16x32_bf16(al0, bh, acc[0][j], 0, 0, 0);
                acc[0][j] = __builtin_amdgcn_mfma_f32_16x16x32_bf16(ah0, bl, acc[0][j], 0, 0, 0);
                acc[1][j] = __builtin_amdgcn_mfma_f32_16x16x32_bf16(ah1, bh, acc[1][j], 0, 0, 0);
                acc[1][j] = __builtin_amdgcn_mfma_f32_16x16x32_bf16(al1, bh, acc[1][j], 0, 0, 0);
                acc[1][j] = __builtin_amdgcn_mfma_f32_16x16x32_bf16(ah1, bl, acc[1][j], 0, 0, 0);
            }
            if (more) {
                bf16x8 h8, l8;
                cvt8(nv, h8, l8);
                *(bf16x8*)&BshH[cur ^ 1][t * 8] = h8;
                *(bf16x8*)&BshL[cur ^ 1][t * 8] = l8;
            }
            cur ^= 1;
        }
    }
    const int sec = n0 >> 9;           // block-uniform
    const int h   = (n0 >> 6) & 7;
    ushort_t* tw  = stile[w];
    const int b = m0 >> 10, nnb = m0 & 1023;
    if (sec < 2) {
        ushort_t* Hp = sec ? Kh : Qh;
        ushort_t* Lp = sec ? Kl : Ql;
        const float qsc = sec ? 1.0f : SCALE_;   // fold attention scale into Q
#pragma unroll
        for (int i = 0; i < 2; ++i)
#pragma unroll
            for (int j = 0; j < 4; ++j)
#pragma unroll
                for (int g = 0; g < 4; ++g) {
                    const float v = acc[i][j][g] * qsc;
                    const ushort_t hb = bf16_rne(v);
                    const ushort_t lb = bf16_rne(v - bf16_f(hb));
                    const int tok = i * 16 + quad * 4 + g;
                    const int d   = j * 16 + ln;
                    tw[tok * 72 + d]        = hb;
                    tw[2304 + tok * 72 + d] = lb;
                }
        __syncthreads();
        const size_t rowbase = ((size_t)(b * 8 + h) * 1024 + nnb) * 64;
        const int dd = (l & 7) * 8;
#pragma unroll
        for (int s = 0; s < 4; ++s) {
            const int tl = s * 8 + (l >> 3);
            const size_t off = rowbase + (size_t)tl * 64 + dd;
            *(us8*)&Hp[off] = *(const us8*)&tw[tl * 72 + dd];
            *(us8*)&Lp[off] = *(const us8*)&tw[2304 + tl * 72 + dd];
        }
    } else {
#pragma unroll
        for (int i = 0; i < 2; ++i)
#pragma unroll
            for (int j = 0; j < 4; ++j)
#pragma unroll
                for (int g = 0; g < 4; ++g)
                    tw[(j * 16 + ln) * 40 + i * 16 + quad * 4 + g] = bf16_rne(acc[i][j][g]);
        __syncthreads();
        const size_t vbase = (size_t)(b * 8 + h) * 65536 + nnb;
#pragma unroll
        for (int p = 0; p < 2; ++p) {
            const int d = (p << 5) + (l >> 1);
            const int c = (l & 1) << 4;
            ushort_t* dst = &Vt[vbase + (size_t)d * 1024 + c];
            *(us8*)dst       = *(const us8*)&tw[d * 40 + c];
            *(us8*)(dst + 8) = *(const us8*)&tw[d * 40 + c + 8];
        }
    }
}

// ---------------------------------------------------------------------------
// out-proj, round 15: 64x64 tile (round-12 occupancy win) + B staged
// directly from fp32 w_out (same in-staging transpose+split; 1 MB,
// L2-resident). w_out layout: [INNER_ k][DIM_ n]; B^T[n][k] = Wo[k*DIM_+n].
// ---------------------------------------------------------------------------
__global__ __launch_bounds__(256) void gemm_out_mfma(
    const ushort_t* __restrict__ Ah, const ushort_t* __restrict__ Al,
    const float* __restrict__ Wo,
    const float* __restrict__ bias, float* __restrict__ C) {
    __shared__ ushort_t BshH[2][2048];
    __shared__ ushort_t BshL[2][2048];
    const int t = threadIdx.x, w = t >> 6, l = t & 63;
    const int ln = l & 15, quad = l >> 4;
    const int n0 = blockIdx.y * 64;
    const int m0 = blockIdx.x * 64 + w * 16;
    f32x4 acc[4] = {};
    {
        const size_t arow0 = (size_t)(m0 + ln) * INNER_;
        const int srow = t >> 2;
        const int sk   = (t & 3) << 3;
        const int gn   = n0 + srow;
        float nv[8];
#pragma unroll
        for (int i = 0; i < 8; ++i)
            nv[i] = Wo[(size_t)(sk + i) * DIM_ + gn];
        {
            bf16x8 h8, l8;
            cvt8(nv, h8, l8);
            *(bf16x8*)&BshH[0][t * 8] = h8;
            *(bf16x8*)&BshL[0][t * 8] = l8;
        }
        int cur = 0;
        for (int k0 = 0; k0 < INNER_; k0 += 32) {
            const bool more = (k0 + 32) < INNER_;
            if (more) {
#pragma unroll
                for (int i = 0; i < 8; ++i)
                    nv[i] = Wo[(size_t)(k0 + 32 + sk + i) * DIM_ + gn];
            }
            __syncthreads();
            const int ko = k0 + quad * 8;
            bf16x8 ah0 = *(const bf16x8*)&Ah[arow0 + ko];
            bf16x8 al0 = *(const bf16x8*)&Al[arow0 + ko];
#pragma unroll
            for (int j = 0; j < 4; ++j) {
                const int slot = (((j << 4) + ln) << 5) + (quad << 3);
                bf16x8 bh = *(const bf16x8*)&BshH[cur][slot];
                bf16x8 bl = *(const bf16x8*)&BshL[cur][slot];
                acc[j] = __builtin_amdgcn_mfma_f32_16x16x32_bf16(ah0, bh, acc[j], 0, 0, 0);
                acc[j] = __builtin_amdgcn_mfma_f32_16x16x32_bf16(al0, bh, acc[j], 0, 0, 0);
                acc[j] = __builtin_amdgcn_mfma_f32_16x16x32_bf16(ah0, bl, acc[j], 0, 0, 0);
            }
            if (more) {
                bf16x8 h8, l8;
                cvt8(nv, h8, l8);
                *(bf16x8*)&BshH[cur ^ 1][t * 8] = h8;
                *(bf16x8*)&BshL[cur ^ 1][t * 8] = l8;
            }
            cur ^= 1;
        }
    }
#pragma unroll
    for (int j = 0; j < 4; ++j) {
        const int col = n0 + j * 16 + ln;
        const float bb = bias[col];
#pragma unroll
        for (int g = 0; g < 4; ++g) {
            const int token = m0 + quad * 4 + g;
            C[(size_t)token * DIM_ + col] = acc[j][g] + bb;
        }
    }
}

// ---------------------------------------------------------------------------
// MFMA kNN attention (frozen round-4 state, single 2048-WG launch).
// ---------------------------------------------------------------------------
__global__ __launch_bounds__(512)
__attribute__((amdgpu_waves_per_eu(4, 4)))
void attn_mfma(const ushort_t* __restrict__ Qh,
               const ushort_t* __restrict__ Ql,
               const ushort_t* __restrict__ Kh,
               const ushort_t* __restrict__ Kl,
               const ushort_t* __restrict__ Vt,
               ushort_t* __restrict__ Oh,
               ushort_t* __restrict__ Ol) {
    __shared__ float sdots[16 * 1024];        // 64 KB
    __shared__ float spartial[4][16][17];     // 4.25 KB j-split merge buffer

    const int t    = threadIdx.x;
    const int w    = t >> 6;        // wave 0..7
    const int l    = t & 63;
    const int ln   = l & 15;
    const int quad = l >> 4;
    const int wg   = blockIdx.x;
    const int bh   = wg & 31;       // XCD-local heads
    const int i0   = (wg >> 5) << 4;

    const size_t bhoff = (size_t)bh << 16;

    // ---- Q fragments (same for all waves; already scaled by 2^-3)
    const ushort_t* qp  = Qh + bhoff + (size_t)(i0 + ln) * 64 + (quad << 3);
    const ushort_t* qlp = Ql + bhoff + (size_t)(i0 + ln) * 64 + (quad << 3);
    bf16x8 qh0 = *(const bf16x8*)qp;
    bf16x8 qh1 = *(const bf16x8*)(qp + 32);
    bf16x8 ql0 = *(const bf16x8*)qlp;
    bf16x8 ql1 = *(const bf16x8*)(qlp + 32);

    // ---- phase-3 V base, computed early for the in-phase-2 prefetch
    const int dblk  = w & 3;
    const int jbase = (w & 4) << 7;   // 0 or 512
    const ushort_t* vp =
        Vt + bhoff + (size_t)((dblk << 4) + ln) * 1024 + (quad << 3) + jbase;
    bf16x8 vpre[8];

    // ---- Phase 1: dots. wave w covers j in [w*128, w*128+128)
    for (int tt = 0; tt < 8; ++tt) {
        const int j0 = ((w << 3) + tt) << 4;
        const ushort_t* kp  = Kh + bhoff + (size_t)(j0 + ln) * 64 + (quad << 3);
        const ushort_t* klp = Kl + bhoff + (size_t)(j0 + ln) * 64 + (quad << 3);
        bf16x8 kh0 = *(const bf16x8*)kp;
        bf16x8 kh1 = *(const bf16x8*)(kp + 32);
        bf16x8 kl0 = *(const bf16x8*)klp;
        bf16x8 kl1 = *(const bf16x8*)(klp + 32);
        f32x4 acc = {0.f, 0.f, 0.f, 0.f};
        acc = __builtin_amdgcn_mfma_f32_16x16x32_bf16(qh0, kh0, acc, 0, 0, 0);
        acc = __builtin_amdgcn_mfma_f32_16x16x32_bf16(qh1, kh1, acc, 0, 0, 0);
        acc = __builtin_amdgcn_mfma_f32_16x16x32_bf16(qh0, kl0, acc, 0, 0, 0);
        acc = __builtin_amdgcn_mfma_f32_16x16x32_bf16(qh1, kl1, acc, 0, 0, 0);
        acc = __builtin_amdgcn_mfma_f32_16x16x32_bf16(ql0, kh0, acc, 0, 0, 0);
        acc = __builtin_amdgcn_mfma_f32_16x16x32_bf16(ql1, kh1, acc, 0, 0, 0);
#pragma unroll
        for (int g = 0; g < 4; ++g) {
            const int row = (quad << 2) + g;
            sdots[(row << 10) + ((j0 + ln) ^ ((row & 7) << 2))] = acc[g];
        }
    }
    __syncthreads();

    // ---- Phase 2: fused 2-row top-k + softmax + in-place bf16 P
    ushort_t* sP = (ushort_t*)sdots;
    {
        const int r0 = w << 1, r1 = r0 | 1;
        const int swz0 = (r0 & 7) << 2, swz1 = (r1 & 7) << 2;
        const float* s0 = &sdots[r0 << 10];
        const float* s1 = &sdots[r1 << 10];
        // lane l holds keys for j = 4l + 256m + i  (m=0..3, i=0..3)
        unsigned key0[16], key1[16];
        float sa0 = 0.f, sb0 = 0.f, sa1 = 0.f, sb1 = 0.f;
#pragma unroll
        for (int m = 0; m < 4; ++m) {
            f32x4 kv0 = *(const f32x4*)&s0[((l << 2) + (m << 8)) ^ swz0];
            f32x4 kv1 = *(const f32x4*)&s1[((l << 2) + (m << 8)) ^ swz1];
#pragma unroll
            for (int i = 0; i < 4; ++i) {
                key0[(m << 2) + i] = f2key(kv0[i]);
                key1[(m << 2) + i] = f2key(kv1[i]);
                sa0 += kv0[i];
                sb0 += kv0[i] * kv0[i];
                sa1 += kv1[i];
                sb1 += kv1[i] * kv1[i];
            }
        }
        // 4 independent reduction chains in one loop (latency overlap)
#pragma unroll
        for (int off = 32; off; off >>= 1) {
            sa0 += __shfl_xor(sa0, off, 64);
            sb0 += __shfl_xor(sb0, off, 64);
            sa1 += __shfl_xor(sa1, off, 64);
            sb1 += __shfl_xor(sb1, off, 64);
        }
        const float mu0 = sa0 * (1.0f / 1024.f);
        const float sg0 = sqrtf(fmaxf(sb0 * (1.0f / 1024.f) - mu0 * mu0, 1e-20f));
        const float mu1 = sa1 * (1.0f / 1024.f);
        const float sg1 = sqrtf(fmaxf(sb1 * (1.0f / 1024.f) - mu1 * mu1, 1e-20f));

        unsigned res0, res1;
        topk2(key0, key1, mu0, sg0, mu1, sg1, res0, res1);

        const float thr0 = key2f(res0), thr1 = key2f(res1);
        float pv0[16], pv1[16];
        float ls0 = 0.f, ls1 = 0.f;
#pragma unroll
        for (int m = 0; m < 16; ++m) {
            float p0 = (key0[m] >= res0) ? __expf(key2f(key0[m]) - thr0) : 0.f;
            float p1 = (key1[m] >= res1) ? __expf(key2f(key1[m]) - thr1) : 0.f;
            pv0[m] = p0;
            pv1[m] = p1;
            ls0 += p0;
            ls1 += p1;
        }
        // ---- prefetch first half of phase-3 V tiles NOW: keys are dead,
        // loads fly during the ls-reduce shuffles + P pack + barrier wait
#pragma unroll
        for (int p = 0; p < 8; ++p)
            vpre[p] = *(const bf16x8*)(vp + p * 32);
#pragma unroll
        for (int off = 32; off; off >>= 1) {
            ls0 += __shfl_xor(ls0, off, 64);
            ls1 += __shfl_xor(ls1, off, 64);
        }
        const float inv0 = 1.f / ls0, inv1 = 1.f / ls1;
        // store P (bf16, phase-3 layout): j = 4l + 256m + i
#pragma unroll
        for (int m = 0; m < 4; ++m) {
            const int g0 = ((l >> 1) + (m << 5)) ^ (r0 & 7);
            const int g1 = ((l >> 1) + (m << 5)) ^ (r1 & 7);
            ushort4 pk0 = make_ushort4(bf16_rne(pv0[(m << 2) + 0] * inv0),
                                       bf16_rne(pv0[(m << 2) + 1] * inv0),
                                       bf16_rne(pv0[(m << 2) + 2] * inv0),
                                       bf16_rne(pv0[(m << 2) + 3] * inv0));
            ushort4 pk1 = make_ushort4(bf16_rne(pv1[(m << 2) + 0] * inv1),
                                       bf16_rne(pv1[(m << 2) + 1] * inv1),
                                       bf16_rne(pv1[(m << 2) + 2] * inv1),
                                       bf16_rne(pv1[(m << 2) + 3] * inv1));
            *(ushort4*)&sP[(r0 << 11) + (g0 << 3) + ((l & 1) << 2)] = pk0;
            *(ushort4*)&sP[(r1 << 11) + (g1 << 3) + ((l & 1) << 2)] = pk1;
        }
    }
    __syncthreads();

    // ---- Phase 3: O = P @ V.  wave w: d-block (w&3), j-half (w&4 ? hi : lo)
    const int prow = ln << 11;
    const int rsw  = ln & 7;
    // issue second-half V loads, overlapped with the first 8 MFMAs
    bf16x8 vnx[8];
#pragma unroll
    for (int p = 0; p < 8; ++p)
        vnx[p] = *(const bf16x8*)(vp + 256 + p * 32);
    f32x4 oa[4] = {};
    __builtin_amdgcn_s_setprio(1);
#pragma unroll
    for (int p = 0; p < 8; ++p) {
        const int j0 = p * 32;
        const int g = ((jbase + j0) >> 3) + quad;
        bf16x8 af = *(const bf16x8*)&sP[prow + ((g ^ rsw) << 3)];
        oa[p & 3] = __builtin_amdgcn_mfma_f32_16x16x32_bf16(af, vpre[p], oa[p & 3], 0, 0, 0);
    }
#pragma unroll
    for (int p = 0; p < 8; ++p) {
        const int j0 = 256 + p * 32;
        const int g = ((jbase + j0) >> 3) + quad;
        bf16x8 af = *(const bf16x8*)&sP[prow + ((g ^ rsw) << 3)];
        oa[p & 3] = __builtin_amdgcn_mfma_f32_16x16x32_bf16(af, vnx[p], oa[p & 3], 0, 0, 0);
    }
    __builtin_amdgcn_s_setprio(0);
    f32x4 oacc = (oa[0] + oa[1]) + (oa[2] + oa[3]);

    if (w & 4) {
#pragma unroll
        for (int g = 0; g < 4; ++g)
            spartial[dblk][(quad << 2) + g][ln] = oacc[g];
    }
    __syncthreads();
    if (!(w & 4)) {
        const int b = bh >> 3, h = bh & 7;
        const size_t obase =
            ((size_t)(b << 10) + i0 + (quad << 2)) * 512 + (h << 6) + (dblk << 4) + ln;
#pragma unroll
        for (int g = 0; g < 4; ++g) {
            const float v = oacc[g] + spartial[dblk][(quad << 2) + g][ln];
            ushort_t hb = bf16_rne(v);
            Oh[obase + (size_t)g * 512] = hb;
            Ol[obase + (size_t)g * 512] = bf16_rne(v - bf16_f(hb));
        }
    }
}

extern "C" void kernel_launch(void* const* d_in, const int* in_sizes, int n_in,
                              void* d_out, int out_size, void* d_ws, size_t ws_size,
                              hipStream_t stream) {
    const float* x     = (const float*)d_in[0];
    const float* w_qkv = (const float*)d_in[1];
    const float* w_out = (const float*)d_in[2];
    const float* b_out = (const float*)d_in[3];
    float*       out   = (float*)d_out;

    const size_t ON  = (size_t)4096 * 512;
    const size_t QK  = (size_t)32 * 1024 * 64;

    ushort_t* p    = (ushort_t*)d_ws;
    ushort_t* Oh   = p;            p += ON;
    ushort_t* Ol   = p;            p += ON;
    ushort_t* Qh   = p;            p += QK;
    ushort_t* Ql   = p;            p += QK;
    ushort_t* Kh   = p;            p += QK;
    ushort_t* Kl   = p;            p += QK;
    ushort_t* Vt   = p;            p += QK;   // 28 MiB total

    // blockIdx.x = m-block so A tiles are XCD-local
    gemm_qkv_mfma<<<dim3(4096 / 128, TRIPLE_ / 64), 256, 0, stream>>>(
        x, w_qkv, Qh, Ql, Kh, Kl, Vt);

    attn_mfma<<<dim3(B_ * H_ * (N_ / 16)), 512, 0, stream>>>(Qh, Ql, Kh, Kl,
                                                             Vt, Oh, Ol);

    gemm_out_mfma<<<dim3(4096 / 64, DIM_ / 64), 256, 0, stream>>>(
        Oh, Ol, w_out, b_out, out);
}

// Round 16
// 217.371 us; speedup vs baseline: 1.4475x; 1.0376x over previous
//
#include <hip/hip_runtime.h>
#include <cstddef>

#define B_      4
#define N_      1024
#define DIM_    512
#define H_      8
#define D_      64
#define INNER_  512
#define TRIPLE_ 1536
#define KK_     716        // int(1024 * 0.7)
#define SCALE_  0.125f     // 64^-0.5

typedef short bf16x8 __attribute__((ext_vector_type(8)));
typedef float f32x4  __attribute__((ext_vector_type(4)));
typedef unsigned short ushort_t;
typedef ushort_t us8 __attribute__((ext_vector_type(8)));

__device__ __forceinline__ unsigned short bf16_rne(float f) {
    unsigned u = __float_as_uint(f);
    return (unsigned short)((u + 0x7FFFu + ((u >> 16) & 1u)) >> 16);
}
__device__ __forceinline__ float bf16_f(unsigned short s) {
    return __uint_as_float((unsigned)s << 16);
}
// order-preserving float->uint key (descending float == descending uint)
__device__ __forceinline__ unsigned f2key(float f) {
    unsigned u = __float_as_uint(f);
    return u ^ ((u & 0x80000000u) ? 0xFFFFFFFFu : 0x80000000u);
}
__device__ __forceinline__ float key2f(unsigned k) {
    unsigned u = (k & 0x80000000u) ? (k ^ 0x80000000u) : ~k;
    return __uint_as_float(u);
}
// wave-wide count of per-lane tallies lc in [0,16] via 5 bit-plane ballots
__device__ __forceinline__ int wave_count(int lc) {
    int c = __popcll(__ballot(lc & 1));
    c += __popcll(__ballot(lc & 2)) << 1;
    c += __popcll(__ballot(lc & 4)) << 2;
    c += __popcll(__ballot(lc & 8)) << 3;
    c += __popcll(__ballot(lc & 16)) << 4;
    return c;
}
__device__ __forceinline__ int count_ge(const unsigned* key, unsigned kt) {
    int lc = 0;
#pragma unroll
    for (int m = 0; m < 16; ++m) lc += (key[m] >= kt) ? 1 : 0;
    return wave_count(lc);
}
// guaranteed-exact uint bisection fallback (rare path)
__device__ __forceinline__ unsigned bisect_exact(const unsigned* key,
                                                 bool hlo, bool hhi,
                                                 float tlo, float thi) {
    unsigned klo = hlo ? f2key(tlo) : 0u;
    unsigned khi = hhi ? f2key(thi) : 0xFFFFFFFFu;
    while (khi - klo > 1u) {
        const unsigned km = klo + ((khi - klo) >> 1);
        const int c = count_ge(key, km);
        if (c >= KK_) { klo = km; if (c == KK_) break; }
        else khi = km;
    }
    return klo;
}
// dual-row interpolation-seeded secant search, chains interleaved for latency
__device__ __forceinline__ void topk2(const unsigned* key0, const unsigned* key1,
                                      float mu0, float sg0, float mu1, float sg1,
                                      unsigned& out0, unsigned& out1) {
    bool done0 = false, done1 = false;
    float tlo0 = 0.f, thi0 = 0.f, tlo1 = 0.f, thi1 = 0.f;
    int   clo0 = 0,   chi0 = 0,   clo1 = 0,   chi1 = 0;
    bool  hlo0 = false, hhi0 = false, hlo1 = false, hhi1 = false;
    float t0 = mu0 - 0.52189f * sg0;      // seed at the 716/1024 quantile
    float t1 = mu1 - 0.52189f * sg1;
    unsigned res0 = 0u, res1 = 0u;
    for (int it = 0; it < 10; ++it) {
        if (done0 & done1) break;
        const unsigned kt0 = f2key(t0);
        const unsigned kt1 = f2key(t1);
        int lc0 = 0, lc1 = 0;
#pragma unroll
        for (int m = 0; m < 16; ++m) {
            lc0 += (key0[m] >= kt0) ? 1 : 0;
            lc1 += (key1[m] >= kt1) ? 1 : 0;
        }
        const int c0 = wave_count(lc0);
        const int c1 = wave_count(lc1);
        if (!done0) {
            if (c0 == KK_) { res0 = kt0; done0 = true; }
            else {
                if (c0 > KK_) { tlo0 = t0; clo0 = c0; hlo0 = true; }
                else          { thi0 = t0; chi0 = c0; hhi0 = true; }
                float tn;
                if (hlo0 && hhi0) {
                    tn = tlo0 + (thi0 - tlo0) * ((float)(clo0 - KK_) / (float)(clo0 - chi0));
                } else {
                    const float z    = (t0 - mu0) / sg0;
                    const float dens = fmaxf(408.5f * __expf(-0.5f * z * z) / sg0, 1.f);
                    tn = t0 + (float)(c0 - KK_) / dens;
                }
                if (hlo0 && !(tn > tlo0)) tn = hhi0 ? 0.5f * (tlo0 + thi0) : tlo0 + 0.25f * sg0;
                if (hhi0 && !(tn < thi0)) tn = hlo0 ? 0.5f * (tlo0 + thi0) : thi0 - 0.25f * sg0;
                t0 = tn;
            }
        }
        if (!done1) {
            if (c1 == KK_) { res1 = kt1; done1 = true; }
            else {
                if (c1 > KK_) { tlo1 = t1; clo1 = c1; hlo1 = true; }
                else          { thi1 = t1; chi1 = c1; hhi1 = true; }
                float tn;
                if (hlo1 && hhi1) {
                    tn = tlo1 + (thi1 - tlo1) * ((float)(clo1 - KK_) / (float)(clo1 - chi1));
                } else {
                    const float z    = (t1 - mu1) / sg1;
                    const float dens = fmaxf(408.5f * __expf(-0.5f * z * z) / sg1, 1.f);
                    tn = t1 + (float)(c1 - KK_) / dens;
                }
                if (hlo1 && !(tn > tlo1)) tn = hhi1 ? 0.5f * (tlo1 + thi1) : tlo1 + 0.25f * sg1;
                if (hhi1 && !(tn < thi1)) tn = hlo1 ? 0.5f * (tlo1 + thi1) : thi1 - 0.25f * sg1;
                t1 = tn;
            }
        }
    }
    if (!done0) res0 = bisect_exact(key0, hlo0, hhi0, tlo0, thi0);
    if (!done1) res1 = bisect_exact(key1, hlo1, hhi1, tlo1, thi1);
    out0 = res0;
    out1 = res1;
}
// load 8 contiguous f32, emit hi/lo bf16 fragments
__device__ __forceinline__ void split8(const float* __restrict__ src,
                                       bf16x8& h8, bf16x8& l8) {
    float4 a = *(const float4*)src;
    float4 b = *(const float4*)(src + 4);
    float v[8] = {a.x, a.y, a.z, a.w, b.x, b.y, b.z, b.w};
#pragma unroll
    for (int i = 0; i < 8; ++i) {
        ushort_t hb = bf16_rne(v[i]);
        h8[i] = (short)hb;
        l8[i] = (short)bf16_rne(v[i] - bf16_f(hb));
    }
}

// ---------------------------------------------------------------------------
// Fused prep: blocks [0,1024) split X fp32 -> hi/lo bf16; blocks
// [1024,1792) transpose+split w_qkv; blocks [1792,2048) transpose+split
// w_out. One launch.
// ---------------------------------------------------------------------------
__global__ __launch_bounds__(256) void prep_split(const float* __restrict__ X,
                                                  const float* __restrict__ Wq,
                                                  const float* __restrict__ Wo,
                                                  ushort_t* __restrict__ Xh,
                                                  ushort_t* __restrict__ Xl,
                                                  ushort_t* __restrict__ WqTh,
                                                  ushort_t* __restrict__ WqTl,
                                                  ushort_t* __restrict__ WoTh,
                                                  ushort_t* __restrict__ WoTl) {
    __shared__ float tile[32][33];
    const int bid = blockIdx.x;
    if (bid < 1024) {
        const int idx = (bid * 256 + threadIdx.x) * 8;
        bf16x8 h8, l8;
        split8(&X[idx], h8, l8);
        *(bf16x8*)&Xh[idx] = h8;
        *(bf16x8*)&Xl[idx] = l8;
        return;
    }
    const int wb = bid - 1024;          // 0..1023
    const int bx = wb & 63, by = wb >> 6;
    const bool isQ = bx < 48;
    const int  nb  = (isQ ? bx : bx - 48) * 32;
    const int  kb  = by * 32;
    const int  Nn  = isQ ? TRIPLE_ : DIM_;
    const float* W = isQ ? Wq : Wo;
    ushort_t* Th   = isQ ? WqTh : WoTh;
    ushort_t* Tl   = isQ ? WqTl : WoTl;
    const int tx = threadIdx.x & 31, ty = threadIdx.x >> 5;   // ty 0..7
    for (int yy = ty; yy < 32; yy += 8)
        tile[yy][tx] = W[(size_t)(kb + yy) * Nn + nb + tx];
    __syncthreads();
    for (int yy = ty; yy < 32; yy += 8) {
        float v = tile[tx][yy];
        ushort_t hb = bf16_rne(v);
        size_t idx = (size_t)(nb + yy) * DIM_ + kb + tx;
        Th[idx] = hb;
        Tl[idx] = bf16_rne(v - bf16_f(hb));
    }
}

// ---------------------------------------------------------------------------
// qkv GEMM (round-12 best state): pre-split bf16 hi/lo A, B tiles
// double-buffered in LDS via VGPR+ds_write, loads issued before the
// barrier. 128x64 tile, 768 blocks = 3 blocks/CU.
// Q section epilogue pre-folds the attention SCALE (2^-3, exact in bf16).
// ---------------------------------------------------------------------------
__global__ __launch_bounds__(256) void gemm_qkv_mfma(
    const ushort_t* __restrict__ Ah, const ushort_t* __restrict__ Al,
    const ushort_t* __restrict__ Wh, const ushort_t* __restrict__ Wl,
    ushort_t* __restrict__ Qh, ushort_t* __restrict__ Ql,
    ushort_t* __restrict__ Kh, ushort_t* __restrict__ Kl,
    ushort_t* __restrict__ Vt) {
    __shared__ ushort_t stile[4][4608];   // 36 KB epilogue scratch
    __shared__ ushort_t BshH[2][2048];    // 8 KB x2 double buffer
    __shared__ ushort_t BshL[2][2048];
    const int t = threadIdx.x, w = t >> 6, l = t & 63;
    const int ln = l & 15, quad = l >> 4;
    const int n0 = blockIdx.y * 64;
    const int m0 = blockIdx.x * 128 + w * 32;
    f32x4 acc[2][4] = {};
    {
        const size_t arow0 = (size_t)(m0 + ln) * DIM_;
        const size_t arow1 = (size_t)(m0 + 16 + ln) * DIM_;
        const int srow = t >> 2;            // 0..63  (staging row)
        const int sk   = (t & 3) << 3;      // 0,8,16,24
        const size_t gb = (size_t)(n0 + srow) * DIM_ + sk;
        us8 nh = *(const us8*)&Wh[gb];
        us8 nl = *(const us8*)&Wl[gb];
        *(us8*)&BshH[0][t * 8] = nh;
        *(us8*)&BshL[0][t * 8] = nl;
        int cur = 0;
        for (int k0 = 0; k0 < DIM_; k0 += 32) {
            const bool more = (k0 + 32) < DIM_;
            const size_t gnext = gb + (size_t)(more ? k0 + 32 : 0);
            nh = *(const us8*)&Wh[gnext];           // issue BEFORE barrier
            nl = *(const us8*)&Wl[gnext];
            __syncthreads();                        // buf[cur] ready
            const int ko = k0 + quad * 8;
            bf16x8 ah0 = *(const bf16x8*)&Ah[arow0 + ko];
            bf16x8 al0 = *(const bf16x8*)&Al[arow0 + ko];
            bf16x8 ah1 = *(const bf16x8*)&Ah[arow1 + ko];
            bf16x8 al1 = *(const bf16x8*)&Al[arow1 + ko];
#pragma unroll
            for (int j = 0; j < 4; ++j) {
                const int slot = (((j << 4) + ln) << 5) + (quad << 3);
                bf16x8 bh = *(const bf16x8*)&BshH[cur][slot];
                bf16x8 bl = *(const bf16x8*)&BshL[cur][slot];
                acc[0][j] = __builtin_amdgcn_mfma_f32_16x16x32_bf16(ah0, bh, acc[0][j], 0, 0, 0);
                acc[0][j] = __builtin_amdgcn_mfma_f32_16x16x32_bf16(al0, bh, acc[0][j], 0, 0, 0);
                acc[0][j] = __builtin_amdgcn_mfma_f32_16x16x32_bf16(ah0, bl, acc[0][j], 0, 0, 0);
                acc[1][j] = __builtin_amdgcn_mfma_f32_16x16x32_bf16(ah1, bh, acc[1][j], 0, 0, 0);
                acc[1][j] = __builtin_amdgcn_mfma_f32_16x16x32_bf16(al1, bh, acc[1][j], 0, 0, 0);
                acc[1][j] = __builtin_amdgcn_mfma_f32_16x16x32_bf16(ah1, bl, acc[1][j], 0, 0, 0);
            }
            if (more) {
                *(us8*)&BshH[cur ^ 1][t * 8] = nh;
                *(us8*)&BshL[cur ^ 1][t * 8] = nl;
            }
            cur ^= 1;
        }
    }
    const int sec = n0 >> 9;           // block-uniform
    const int h   = (n0 >> 6) & 7;
    ushort_t* tw  = stile[w];
    const int b = m0 >> 10, nnb = m0 & 1023;
    if (sec < 2) {
        ushort_t* Hp = sec ? Kh : Qh;
        ushort_t* Lp = sec ? Kl : Ql;
        const float qsc = sec ? 1.0f : SCALE_;   // fold attention scale into Q
#pragma unroll
        for (int i = 0; i < 2; ++i)
#pragma unroll
            for (int j = 0; j < 4; ++j)
#pragma unroll
                for (int g = 0; g < 4; ++g) {
                    const float v = acc[i][j][g] * qsc;
                    const ushort_t hb = bf16_rne(v);
                    const ushort_t lb = bf16_rne(v - bf16_f(hb));
                    const int tok = i * 16 + quad * 4 + g;
                    const int d   = j * 16 + ln;
                    tw[tok * 72 + d]        = hb;
                    tw[2304 + tok * 72 + d] = lb;
                }
        __syncthreads();
        const size_t rowbase = ((size_t)(b * 8 + h) * 1024 + nnb) * 64;
        const int dd = (l & 7) * 8;
#pragma unroll
        for (int s = 0; s < 4; ++s) {
            const int tl = s * 8 + (l >> 3);
            const size_t off = rowbase + (size_t)tl * 64 + dd;
            *(us8*)&Hp[off] = *(const us8*)&tw[tl * 72 + dd];
            *(us8*)&Lp[off] = *(const us8*)&tw[2304 + tl * 72 + dd];
        }
    } else {
#pragma unroll
        for (int i = 0; i < 2; ++i)
#pragma unroll
            for (int j = 0; j < 4; ++j)
#pragma unroll
                for (int g = 0; g < 4; ++g)
                    tw[(j * 16 + ln) * 40 + i * 16 + quad * 4 + g] = bf16_rne(acc[i][j][g]);
        __syncthreads();
        const size_t vbase = (size_t)(b * 8 + h) * 65536 + nnb;
#pragma unroll
        for (int p = 0; p < 2; ++p) {
            const int d = (p << 5) + (l >> 1);
            const int c = (l & 1) << 4;
            ushort_t* dst = &Vt[vbase + (size_t)d * 1024 + c];
            *(us8*)dst       = *(const us8*)&tw[d * 40 + c];
            *(us8*)(dst + 8) = *(const us8*)&tw[d * 40 + c + 8];
        }
    }
}

// ---------------------------------------------------------------------------
// out-proj (round-12 win): 64x64 tile, grid (64,8) = 512 WGs = 2 WG/CU =
// 8 waves/CU. Each wave owns 16 rows (acc[4], 12 MFMAs/k-step).
// ---------------------------------------------------------------------------
__global__ __launch_bounds__(256) void gemm_out_mfma(
    const ushort_t* __restrict__ Ah, const ushort_t* __restrict__ Al,
    const ushort_t* __restrict__ Wh, const ushort_t* __restrict__ Wl,
    const float* __restrict__ bias, float* __restrict__ C) {
    __shared__ ushort_t BshH[2][2048];
    __shared__ ushort_t BshL[2][2048];
    const int t = threadIdx.x, w = t >> 6, l = t & 63;
    const int ln = l & 15, quad = l >> 4;
    const int n0 = blockIdx.y * 64;
    const int m0 = blockIdx.x * 64 + w * 16;
    f32x4 acc[4] = {};
    {
        const size_t arow0 = (size_t)(m0 + ln) * INNER_;
        const int srow = t >> 2;
        const int sk   = (t & 3) << 3;
        const size_t gb = (size_t)(n0 + srow) * INNER_ + sk;
        us8 nh = *(const us8*)&Wh[gb];
        us8 nl = *(const us8*)&Wl[gb];
        *(us8*)&BshH[0][t * 8] = nh;
        *(us8*)&BshL[0][t * 8] = nl;
        int cur = 0;
        for (int k0 = 0; k0 < INNER_; k0 += 32) {
            const bool more = (k0 + 32) < INNER_;
            const size_t gnext = gb + (size_t)(more ? k0 + 32 : 0);
            nh = *(const us8*)&Wh[gnext];
            nl = *(const us8*)&Wl[gnext];
            __syncthreads();
            const int ko = k0 + quad * 8;
            bf16x8 ah0 = *(const bf16x8*)&Ah[arow0 + ko];
            bf16x8 al0 = *(const bf16x8*)&Al[arow0 + ko];
#pragma unroll
            for (int j = 0; j < 4; ++j) {
                const int slot = (((j << 4) + ln) << 5) + (quad << 3);
                bf16x8 bh = *(const bf16x8*)&BshH[cur][slot];
                bf16x8 bl = *(const bf16x8*)&BshL[cur][slot];
                acc[j] = __builtin_amdgcn_mfma_f32_16x16x32_bf16(ah0, bh, acc[j], 0, 0, 0);
                acc[j] = __builtin_amdgcn_mfma_f32_16x16x32_bf16(al0, bh, acc[j], 0, 0, 0);
                acc[j] = __builtin_amdgcn_mfma_f32_16x16x32_bf16(ah0, bl, acc[j], 0, 0, 0);
            }
            if (more) {
                *(us8*)&BshH[cur ^ 1][t * 8] = nh;
                *(us8*)&BshL[cur ^ 1][t * 8] = nl;
            }
            cur ^= 1;
        }
    }
#pragma unroll
    for (int j = 0; j < 4; ++j) {
        const int col = n0 + j * 16 + ln;
        const float bb = bias[col];
#pragma unroll
        for (int g = 0; g < 4; ++g) {
            const int token = m0 + quad * 4 + g;
            C[(size_t)token * DIM_ + col] = acc[j][g] + bb;
        }
    }
}

// ---------------------------------------------------------------------------
// MFMA kNN attention (frozen round-4 state, single 2048-WG launch).
// ---------------------------------------------------------------------------
__global__ __launch_bounds__(512)
__attribute__((amdgpu_waves_per_eu(4, 4)))
void attn_mfma(const ushort_t* __restrict__ Qh,
               const ushort_t* __restrict__ Ql,
               const ushort_t* __restrict__ Kh,
               const ushort_t* __restrict__ Kl,
               const ushort_t* __restrict__ Vt,
               ushort_t* __restrict__ Oh,
               ushort_t* __restrict__ Ol) {
    __shared__ float sdots[16 * 1024];        // 64 KB
    __shared__ float spartial[4][16][17];     // 4.25 KB j-split merge buffer

    const int t    = threadIdx.x;
    const int w    = t >> 6;        // wave 0..7
    const int l    = t & 63;
    const int ln   = l & 15;
    const int quad = l >> 4;
    const int wg   = blockIdx.x;
    const int bh   = wg & 31;       // XCD-local heads
    const int i0   = (wg >> 5) << 4;

    const size_t bhoff = (size_t)bh << 16;

    // ---- Q fragments (same for all waves; already scaled by 2^-3)
    const ushort_t* qp  = Qh + bhoff + (size_t)(i0 + ln) * 64 + (quad << 3);
    const ushort_t* qlp = Ql + bhoff + (size_t)(i0 + ln) * 64 + (quad << 3);
    bf16x8 qh0 = *(const bf16x8*)qp;
    bf16x8 qh1 = *(const bf16x8*)(qp + 32);
    bf16x8 ql0 = *(const bf16x8*)qlp;
    bf16x8 ql1 = *(const bf16x8*)(qlp + 32);

    // ---- phase-3 V base, computed early for the in-phase-2 prefetch
    const int dblk  = w & 3;
    const int jbase = (w & 4) << 7;   // 0 or 512
    const ushort_t* vp =
        Vt + bhoff + (size_t)((dblk << 4) + ln) * 1024 + (quad << 3) + jbase;
    bf16x8 vpre[8];

    // ---- Phase 1: dots. wave w covers j in [w*128, w*128+128)
    for (int tt = 0; tt < 8; ++tt) {
        const int j0 = ((w << 3) + tt) << 4;
        const ushort_t* kp  = Kh + bhoff + (size_t)(j0 + ln) * 64 + (quad << 3);
        const ushort_t* klp = Kl + bhoff + (size_t)(j0 + ln) * 64 + (quad << 3);
        bf16x8 kh0 = *(const bf16x8*)kp;
        bf16x8 kh1 = *(const bf16x8*)(kp + 32);
        bf16x8 kl0 = *(const bf16x8*)klp;
        bf16x8 kl1 = *(const bf16x8*)(klp + 32);
        f32x4 acc = {0.f, 0.f, 0.f, 0.f};
        acc = __builtin_amdgcn_mfma_f32_16x16x32_bf16(qh0, kh0, acc, 0, 0, 0);
        acc = __builtin_amdgcn_mfma_f32_16x16x32_bf16(qh1, kh1, acc, 0, 0, 0);
        acc = __builtin_amdgcn_mfma_f32_16x16x32_bf16(qh0, kl0, acc, 0, 0, 0);
        acc = __builtin_amdgcn_mfma_f32_16x16x32_bf16(qh1, kl1, acc, 0, 0, 0);
        acc = __builtin_amdgcn_mfma_f32_16x16x32_bf16(ql0, kh0, acc, 0, 0, 0);
        acc = __builtin_amdgcn_mfma_f32_16x16x32_bf16(ql1, kh1, acc, 0, 0, 0);
#pragma unroll
        for (int g = 0; g < 4; ++g) {
            const int row = (quad << 2) + g;
            sdots[(row << 10) + ((j0 + ln) ^ ((row & 7) << 2))] = acc[g];
        }
    }
    __syncthreads();

    // ---- Phase 2: fused 2-row top-k + softmax + in-place bf16 P
    ushort_t* sP = (ushort_t*)sdots;
    {
        const int r0 = w << 1, r1 = r0 | 1;
        const int swz0 = (r0 & 7) << 2, swz1 = (r1 & 7) << 2;
        const float* s0 = &sdots[r0 << 10];
        const float* s1 = &sdots[r1 << 10];
        // lane l holds keys for j = 4l + 256m + i  (m=0..3, i=0..3)
        unsigned key0[16], key1[16];
        float sa0 = 0.f, sb0 = 0.f, sa1 = 0.f, sb1 = 0.f;
#pragma unroll
        for (int m = 0; m < 4; ++m) {
            f32x4 kv0 = *(const f32x4*)&s0[((l << 2) + (m << 8)) ^ swz0];
            f32x4 kv1 = *(const f32x4*)&s1[((l << 2) + (m << 8)) ^ swz1];
#pragma unroll
            for (int i = 0; i < 4; ++i) {
                key0[(m << 2) + i] = f2key(kv0[i]);
                key1[(m << 2) + i] = f2key(kv1[i]);
                sa0 += kv0[i];
                sb0 += kv0[i] * kv0[i];
                sa1 += kv1[i];
                sb1 += kv1[i] * kv1[i];
            }
        }
        // 4 independent reduction chains in one loop (latency overlap)
#pragma unroll
        for (int off = 32; off; off >>= 1) {
            sa0 += __shfl_xor(sa0, off, 64);
            sb0 += __shfl_xor(sb0, off, 64);
            sa1 += __shfl_xor(sa1, off, 64);
            sb1 += __shfl_xor(sb1, off, 64);
        }
        const float mu0 = sa0 * (1.0f / 1024.f);
        const float sg0 = sqrtf(fmaxf(sb0 * (1.0f / 1024.f) - mu0 * mu0, 1e-20f));
        const float mu1 = sa1 * (1.0f / 1024.f);
        const float sg1 = sqrtf(fmaxf(sb1 * (1.0f / 1024.f) - mu1 * mu1, 1e-20f));

        unsigned res0, res1;
        topk2(key0, key1, mu0, sg0, mu1, sg1, res0, res1);

        const float thr0 = key2f(res0), thr1 = key2f(res1);
        float pv0[16], pv1[16];
        float ls0 = 0.f, ls1 = 0.f;
#pragma unroll
        for (int m = 0; m < 16; ++m) {
            float p0 = (key0[m] >= res0) ? __expf(key2f(key0[m]) - thr0) : 0.f;
            float p1 = (key1[m] >= res1) ? __expf(key2f(key1[m]) - thr1) : 0.f;
            pv0[m] = p0;
            pv1[m] = p1;
            ls0 += p0;
            ls1 += p1;
        }
        // ---- prefetch first half of phase-3 V tiles NOW: keys are dead,
        // loads fly during the ls-reduce shuffles + P pack + barrier wait
#pragma unroll
        for (int p = 0; p < 8; ++p)
            vpre[p] = *(const bf16x8*)(vp + p * 32);
#pragma unroll
        for (int off = 32; off; off >>= 1) {
            ls0 += __shfl_xor(ls0, off, 64);
            ls1 += __shfl_xor(ls1, off, 64);
        }
        const float inv0 = 1.f / ls0, inv1 = 1.f / ls1;
        // store P (bf16, phase-3 layout): j = 4l + 256m + i
#pragma unroll
        for (int m = 0; m < 4; ++m) {
            const int g0 = ((l >> 1) + (m << 5)) ^ (r0 & 7);
            const int g1 = ((l >> 1) + (m << 5)) ^ (r1 & 7);
            ushort4 pk0 = make_ushort4(bf16_rne(pv0[(m << 2) + 0] * inv0),
                                       bf16_rne(pv0[(m << 2) + 1] * inv0),
                                       bf16_rne(pv0[(m << 2) + 2] * inv0),
                                       bf16_rne(pv0[(m << 2) + 3] * inv0));
            ushort4 pk1 = make_ushort4(bf16_rne(pv1[(m << 2) + 0] * inv1),
                                       bf16_rne(pv1[(m << 2) + 1] * inv1),
                                       bf16_rne(pv1[(m << 2) + 2] * inv1),
                                       bf16_rne(pv1[(m << 2) + 3] * inv1));
            *(ushort4*)&sP[(r0 << 11) + (g0 << 3) + ((l & 1) << 2)] = pk0;
            *(ushort4*)&sP[(r1 << 11) + (g1 << 3) + ((l & 1) << 2)] = pk1;
        }
    }
    __syncthreads();

    // ---- Phase 3: O = P @ V.  wave w: d-block (w&3), j-half (w&4 ? hi : lo)
    const int prow = ln << 11;
    const int rsw  = ln & 7;
    // issue second-half V loads, overlapped with the first 8 MFMAs
    bf16x8 vnx[8];
#pragma unroll
    for (int p = 0; p < 8; ++p)
        vnx[p] = *(const bf16x8*)(vp + 256 + p * 32);
    f32x4 oa[4] = {};
    __builtin_amdgcn_s_setprio(1);
#pragma unroll
    for (int p = 0; p < 8; ++p) {
        const int j0 = p * 32;
        const int g = ((jbase + j0) >> 3) + quad;
        bf16x8 af = *(const bf16x8*)&sP[prow + ((g ^ rsw) << 3)];
        oa[p & 3] = __builtin_amdgcn_mfma_f32_16x16x32_bf16(af, vpre[p], oa[p & 3], 0, 0, 0);
    }
#pragma unroll
    for (int p = 0; p < 8; ++p) {
        const int j0 = 256 + p * 32;
        const int g = ((jbase + j0) >> 3) + quad;
        bf16x8 af = *(const bf16x8*)&sP[prow + ((g ^ rsw) << 3)];
        oa[p & 3] = __builtin_amdgcn_mfma_f32_16x16x32_bf16(af, vnx[p], oa[p & 3], 0, 0, 0);
    }
    __builtin_amdgcn_s_setprio(0);
    f32x4 oacc = (oa[0] + oa[1]) + (oa[2] + oa[3]);

    if (w & 4) {
#pragma unroll
        for (int g = 0; g < 4; ++g)
            spartial[dblk][(quad << 2) + g][ln] = oacc[g];
    }
    __syncthreads();
    if (!(w & 4)) {
        const int b = bh >> 3, h = bh & 7;
        const size_t obase =
            ((size_t)(b << 10) + i0 + (quad << 2)) * 512 + (h << 6) + (dblk << 4) + ln;
#pragma unroll
        for (int g = 0; g < 4; ++g) {
            const float v = oacc[g] + spartial[dblk][(quad << 2) + g][ln];
            ushort_t hb = bf16_rne(v);
            Oh[obase + (size_t)g * 512] = hb;
            Ol[obase + (size_t)g * 512] = bf16_rne(v - bf16_f(hb));
        }
    }
}

extern "C" void kernel_launch(void* const* d_in, const int* in_sizes, int n_in,
                              void* d_out, int out_size, void* d_ws, size_t ws_size,
                              hipStream_t stream) {
    const float* x     = (const float*)d_in[0];
    const float* w_qkv = (const float*)d_in[1];
    const float* w_out = (const float*)d_in[2];
    const float* b_out = (const float*)d_in[3];
    float*       out   = (float*)d_out;

    const size_t ON  = (size_t)4096 * 512;
    const size_t WQT = (size_t)1536 * 512;
    const size_t WOT = (size_t)512 * 512;
    const size_t QK  = (size_t)32 * 1024 * 64;

    ushort_t* p    = (ushort_t*)d_ws;
    ushort_t* Oh   = p;            p += ON;
    ushort_t* Ol   = p;            p += ON;
    ushort_t* WqTh = p;            p += WQT;
    ushort_t* WqTl = p;            p += WQT;
    ushort_t* WoTh = p;            p += WOT;
    ushort_t* WoTl = p;            p += WOT;
    ushort_t* Qh   = p;            p += QK;
    ushort_t* Ql   = p;            p += QK;
    ushort_t* Kh   = p;            p += QK;
    ushort_t* Kl   = p;            p += QK;
    ushort_t* Vt   = p;            p += QK;   // total exactly 32 MiB

    // Xh/Xl alias Oh/Ol: live only until gemm_qkv completes; attn writes
    // Oh/Ol strictly after (stream-ordered).
    ushort_t* Xh = Oh;
    ushort_t* Xl = Ol;

    prep_split<<<dim3(2048), 256, 0, stream>>>(x, w_qkv, w_out, Xh, Xl,
                                               WqTh, WqTl, WoTh, WoTl);

    // blockIdx.x = m-block so A tiles are XCD-local
    gemm_qkv_mfma<<<dim3(4096 / 128, TRIPLE_ / 64), 256, 0, stream>>>(
        Xh, Xl, WqTh, WqTl, Qh, Ql, Kh, Kl, Vt);

    attn_mfma<<<dim3(B_ * H_ * (N_ / 16)), 512, 0, stream>>>(Qh, Ql, Kh, Kl,
                                                             Vt, Oh, Ol);

    gemm_out_mfma<<<dim3(4096 / 64, DIM_ / 64), 256, 0, stream>>>(
        Oh, Ol, WoTh, WoTl, b_out, out);
}

// Round 17
// 215.506 us; speedup vs baseline: 1.4600x; 1.0087x over previous
//
#include <hip/hip_runtime.h>
#include <cstddef>

#define B_      4
#define N_      1024
#define DIM_    512
#define H_      8
#define D_      64
#define INNER_  512
#define TRIPLE_ 1536
#define KK_     716        // int(1024 * 0.7)
#define SCALE_  0.125f     // 64^-0.5

typedef short bf16x8 __attribute__((ext_vector_type(8)));
typedef float f32x4  __attribute__((ext_vector_type(4)));
typedef unsigned short ushort_t;
typedef ushort_t us8 __attribute__((ext_vector_type(8)));

__device__ __forceinline__ unsigned short bf16_rne(float f) {
    unsigned u = __float_as_uint(f);
    return (unsigned short)((u + 0x7FFFu + ((u >> 16) & 1u)) >> 16);
}
__device__ __forceinline__ float bf16_f(unsigned short s) {
    return __uint_as_float((unsigned)s << 16);
}
// order-preserving float->uint key (descending float == descending uint)
__device__ __forceinline__ unsigned f2key(float f) {
    unsigned u = __float_as_uint(f);
    return u ^ ((u & 0x80000000u) ? 0xFFFFFFFFu : 0x80000000u);
}
__device__ __forceinline__ float key2f(unsigned k) {
    unsigned u = (k & 0x80000000u) ? (k ^ 0x80000000u) : ~k;
    return __uint_as_float(u);
}
// wave-wide count of per-lane tallies lc in [0,16] via 5 bit-plane ballots
__device__ __forceinline__ int wave_count(int lc) {
    int c = __popcll(__ballot(lc & 1));
    c += __popcll(__ballot(lc & 2)) << 1;
    c += __popcll(__ballot(lc & 4)) << 2;
    c += __popcll(__ballot(lc & 8)) << 3;
    c += __popcll(__ballot(lc & 16)) << 4;
    return c;
}
__device__ __forceinline__ int count_ge(const unsigned* key, unsigned kt) {
    int lc = 0;
#pragma unroll
    for (int m = 0; m < 16; ++m) lc += (key[m] >= kt) ? 1 : 0;
    return wave_count(lc);
}
// guaranteed-exact uint bisection fallback (rare path)
__device__ __forceinline__ unsigned bisect_exact(const unsigned* key,
                                                 bool hlo, bool hhi,
                                                 float tlo, float thi) {
    unsigned klo = hlo ? f2key(tlo) : 0u;
    unsigned khi = hhi ? f2key(thi) : 0xFFFFFFFFu;
    while (khi - klo > 1u) {
        const unsigned km = klo + ((khi - klo) >> 1);
        const int c = count_ge(key, km);
        if (c >= KK_) { klo = km; if (c == KK_) break; }
        else khi = km;
    }
    return klo;
}
// dual-row interpolation-seeded secant search, chains interleaved for latency
__device__ __forceinline__ void topk2(const unsigned* key0, const unsigned* key1,
                                      float mu0, float sg0, float mu1, float sg1,
                                      unsigned& out0, unsigned& out1) {
    bool done0 = false, done1 = false;
    float tlo0 = 0.f, thi0 = 0.f, tlo1 = 0.f, thi1 = 0.f;
    int   clo0 = 0,   chi0 = 0,   clo1 = 0,   chi1 = 0;
    bool  hlo0 = false, hhi0 = false, hlo1 = false, hhi1 = false;
    float t0 = mu0 - 0.52189f * sg0;      // seed at the 716/1024 quantile
    float t1 = mu1 - 0.52189f * sg1;
    unsigned res0 = 0u, res1 = 0u;
    for (int it = 0; it < 10; ++it) {
        if (done0 & done1) break;
        const unsigned kt0 = f2key(t0);
        const unsigned kt1 = f2key(t1);
        int lc0 = 0, lc1 = 0;
#pragma unroll
        for (int m = 0; m < 16; ++m) {
            lc0 += (key0[m] >= kt0) ? 1 : 0;
            lc1 += (key1[m] >= kt1) ? 1 : 0;
        }
        const int c0 = wave_count(lc0);
        const int c1 = wave_count(lc1);
        if (!done0) {
            if (c0 == KK_) { res0 = kt0; done0 = true; }
            else {
                if (c0 > KK_) { tlo0 = t0; clo0 = c0; hlo0 = true; }
                else          { thi0 = t0; chi0 = c0; hhi0 = true; }
                float tn;
                if (hlo0 && hhi0) {
                    tn = tlo0 + (thi0 - tlo0) * ((float)(clo0 - KK_) / (float)(clo0 - chi0));
                } else {
                    const float z    = (t0 - mu0) / sg0;
                    const float dens = fmaxf(408.5f * __expf(-0.5f * z * z) / sg0, 1.f);
                    tn = t0 + (float)(c0 - KK_) / dens;
                }
                if (hlo0 && !(tn > tlo0)) tn = hhi0 ? 0.5f * (tlo0 + thi0) : tlo0 + 0.25f * sg0;
                if (hhi0 && !(tn < thi0)) tn = hlo0 ? 0.5f * (tlo0 + thi0) : thi0 - 0.25f * sg0;
                t0 = tn;
            }
        }
        if (!done1) {
            if (c1 == KK_) { res1 = kt1; done1 = true; }
            else {
                if (c1 > KK_) { tlo1 = t1; clo1 = c1; hlo1 = true; }
                else          { thi1 = t1; chi1 = c1; hhi1 = true; }
                float tn;
                if (hlo1 && hhi1) {
                    tn = tlo1 + (thi1 - tlo1) * ((float)(clo1 - KK_) / (float)(clo1 - chi1));
                } else {
                    const float z    = (t1 - mu1) / sg1;
                    const float dens = fmaxf(408.5f * __expf(-0.5f * z * z) / sg1, 1.f);
                    tn = t1 + (float)(c1 - KK_) / dens;
                }
                if (hlo1 && !(tn > tlo1)) tn = hhi1 ? 0.5f * (tlo1 + thi1) : tlo1 + 0.25f * sg1;
                if (hhi1 && !(tn < thi1)) tn = hlo1 ? 0.5f * (tlo1 + thi1) : thi1 - 0.25f * sg1;
                t1 = tn;
            }
        }
    }
    if (!done0) res0 = bisect_exact(key0, hlo0, hhi0, tlo0, thi0);
    if (!done1) res1 = bisect_exact(key1, hlo1, hhi1, tlo1, thi1);
    out0 = res0;
    out1 = res1;
}
// load 8 contiguous f32, emit hi/lo bf16 fragments
__device__ __forceinline__ void split8(const float* __restrict__ src,
                                       bf16x8& h8, bf16x8& l8) {
    float4 a = *(const float4*)src;
    float4 b = *(const float4*)(src + 4);
    float v[8] = {a.x, a.y, a.z, a.w, b.x, b.y, b.z, b.w};
#pragma unroll
    for (int i = 0; i < 8; ++i) {
        ushort_t hb = bf16_rne(v[i]);
        h8[i] = (short)hb;
        l8[i] = (short)bf16_rne(v[i] - bf16_f(hb));
    }
}

// ---------------------------------------------------------------------------
// Fused prep: blocks [0,1024) split X fp32 -> hi/lo bf16; blocks
// [1024,1792) transpose+split w_qkv; blocks [1792,2048) transpose+split
// w_out. One launch.
// ---------------------------------------------------------------------------
__global__ __launch_bounds__(256) void prep_split(const float* __restrict__ X,
                                                  const float* __restrict__ Wq,
                                                  const float* __restrict__ Wo,
                                                  ushort_t* __restrict__ Xh,
                                                  ushort_t* __restrict__ Xl,
                                                  ushort_t* __restrict__ WqTh,
                                                  ushort_t* __restrict__ WqTl,
                                                  ushort_t* __restrict__ WoTh,
                                                  ushort_t* __restrict__ WoTl) {
    __shared__ float tile[32][33];
    const int bid = blockIdx.x;
    if (bid < 1024) {
        const int idx = (bid * 256 + threadIdx.x) * 8;
        bf16x8 h8, l8;
        split8(&X[idx], h8, l8);
        *(bf16x8*)&Xh[idx] = h8;
        *(bf16x8*)&Xl[idx] = l8;
        return;
    }
    const int wb = bid - 1024;          // 0..1023
    const int bx = wb & 63, by = wb >> 6;
    const bool isQ = bx < 48;
    const int  nb  = (isQ ? bx : bx - 48) * 32;
    const int  kb  = by * 32;
    const int  Nn  = isQ ? TRIPLE_ : DIM_;
    const float* W = isQ ? Wq : Wo;
    ushort_t* Th   = isQ ? WqTh : WoTh;
    ushort_t* Tl   = isQ ? WqTl : WoTl;
    const int tx = threadIdx.x & 31, ty = threadIdx.x >> 5;   // ty 0..7
    for (int yy = ty; yy < 32; yy += 8)
        tile[yy][tx] = W[(size_t)(kb + yy) * Nn + nb + tx];
    __syncthreads();
    for (int yy = ty; yy < 32; yy += 8) {
        float v = tile[tx][yy];
        ushort_t hb = bf16_rne(v);
        size_t idx = (size_t)(nb + yy) * DIM_ + kb + tx;
        Th[idx] = hb;
        Tl[idx] = bf16_rne(v - bf16_f(hb));
    }
}

// ---------------------------------------------------------------------------
// qkv GEMM (round-12 best state): pre-split bf16 hi/lo A, B tiles
// double-buffered in LDS via VGPR+ds_write, loads issued before the
// barrier. 128x64 tile, 768 blocks = 3 blocks/CU.
// Q section epilogue pre-folds the attention SCALE (2^-3, exact in bf16).
// ---------------------------------------------------------------------------
__global__ __launch_bounds__(256) void gemm_qkv_mfma(
    const ushort_t* __restrict__ Ah, const ushort_t* __restrict__ Al,
    const ushort_t* __restrict__ Wh, const ushort_t* __restrict__ Wl,
    ushort_t* __restrict__ Qh, ushort_t* __restrict__ Ql,
    ushort_t* __restrict__ Kh, ushort_t* __restrict__ Kl,
    ushort_t* __restrict__ Vt) {
    __shared__ ushort_t stile[4][4608];   // 36 KB epilogue scratch
    __shared__ ushort_t BshH[2][2048];    // 8 KB x2 double buffer
    __shared__ ushort_t BshL[2][2048];
    const int t = threadIdx.x, w = t >> 6, l = t & 63;
    const int ln = l & 15, quad = l >> 4;
    const int n0 = blockIdx.y * 64;
    const int m0 = blockIdx.x * 128 + w * 32;
    f32x4 acc[2][4] = {};
    {
        const size_t arow0 = (size_t)(m0 + ln) * DIM_;
        const size_t arow1 = (size_t)(m0 + 16 + ln) * DIM_;
        const int srow = t >> 2;            // 0..63  (staging row)
        const int sk   = (t & 3) << 3;      // 0,8,16,24
        const size_t gb = (size_t)(n0 + srow) * DIM_ + sk;
        us8 nh = *(const us8*)&Wh[gb];
        us8 nl = *(const us8*)&Wl[gb];
        *(us8*)&BshH[0][t * 8] = nh;
        *(us8*)&BshL[0][t * 8] = nl;
        int cur = 0;
        for (int k0 = 0; k0 < DIM_; k0 += 32) {
            const bool more = (k0 + 32) < DIM_;
            const size_t gnext = gb + (size_t)(more ? k0 + 32 : 0);
            nh = *(const us8*)&Wh[gnext];           // issue BEFORE barrier
            nl = *(const us8*)&Wl[gnext];
            __syncthreads();                        // buf[cur] ready
            const int ko = k0 + quad * 8;
            bf16x8 ah0 = *(const bf16x8*)&Ah[arow0 + ko];
            bf16x8 al0 = *(const bf16x8*)&Al[arow0 + ko];
            bf16x8 ah1 = *(const bf16x8*)&Ah[arow1 + ko];
            bf16x8 al1 = *(const bf16x8*)&Al[arow1 + ko];
#pragma unroll
            for (int j = 0; j < 4; ++j) {
                const int slot = (((j << 4) + ln) << 5) + (quad << 3);
                bf16x8 bh = *(const bf16x8*)&BshH[cur][slot];
                bf16x8 bl = *(const bf16x8*)&BshL[cur][slot];
                acc[0][j] = __builtin_amdgcn_mfma_f32_16x16x32_bf16(ah0, bh, acc[0][j], 0, 0, 0);
                acc[0][j] = __builtin_amdgcn_mfma_f32_16x16x32_bf16(al0, bh, acc[0][j], 0, 0, 0);
                acc[0][j] = __builtin_amdgcn_mfma_f32_16x16x32_bf16(ah0, bl, acc[0][j], 0, 0, 0);
                acc[1][j] = __builtin_amdgcn_mfma_f32_16x16x32_bf16(ah1, bh, acc[1][j], 0, 0, 0);
                acc[1][j] = __builtin_amdgcn_mfma_f32_16x16x32_bf16(al1, bh, acc[1][j], 0, 0, 0);
                acc[1][j] = __builtin_amdgcn_mfma_f32_16x16x32_bf16(ah1, bl, acc[1][j], 0, 0, 0);
            }
            if (more) {
                *(us8*)&BshH[cur ^ 1][t * 8] = nh;
                *(us8*)&BshL[cur ^ 1][t * 8] = nl;
            }
            cur ^= 1;
        }
    }
    const int sec = n0 >> 9;           // block-uniform
    const int h   = (n0 >> 6) & 7;
    ushort_t* tw  = stile[w];
    const int b = m0 >> 10, nnb = m0 & 1023;
    if (sec < 2) {
        ushort_t* Hp = sec ? Kh : Qh;
        ushort_t* Lp = sec ? Kl : Ql;
        const float qsc = sec ? 1.0f : SCALE_;   // fold attention scale into Q
#pragma unroll
        for (int i = 0; i < 2; ++i)
#pragma unroll
            for (int j = 0; j < 4; ++j)
#pragma unroll
                for (int g = 0; g < 4; ++g) {
                    const float v = acc[i][j][g] * qsc;
                    const ushort_t hb = bf16_rne(v);
                    const ushort_t lb = bf16_rne(v - bf16_f(hb));
                    const int tok = i * 16 + quad * 4 + g;
                    const int d   = j * 16 + ln;
                    tw[tok * 72 + d]        = hb;
                    tw[2304 + tok * 72 + d] = lb;
                }
        __syncthreads();
        const size_t rowbase = ((size_t)(b * 8 + h) * 1024 + nnb) * 64;
        const int dd = (l & 7) * 8;
#pragma unroll
        for (int s = 0; s < 4; ++s) {
            const int tl = s * 8 + (l >> 3);
            const size_t off = rowbase + (size_t)tl * 64 + dd;
            *(us8*)&Hp[off] = *(const us8*)&tw[tl * 72 + dd];
            *(us8*)&Lp[off] = *(const us8*)&tw[2304 + tl * 72 + dd];
        }
    } else {
#pragma unroll
        for (int i = 0; i < 2; ++i)
#pragma unroll
            for (int j = 0; j < 4; ++j)
#pragma unroll
                for (int g = 0; g < 4; ++g)
                    tw[(j * 16 + ln) * 40 + i * 16 + quad * 4 + g] = bf16_rne(acc[i][j][g]);
        __syncthreads();
        const size_t vbase = (size_t)(b * 8 + h) * 65536 + nnb;
#pragma unroll
        for (int p = 0; p < 2; ++p) {
            const int d = (p << 5) + (l >> 1);
            const int c = (l & 1) << 4;
            ushort_t* dst = &Vt[vbase + (size_t)d * 1024 + c];
            *(us8*)dst       = *(const us8*)&tw[d * 40 + c];
            *(us8*)(dst + 8) = *(const us8*)&tw[d * 40 + c + 8];
        }
    }
}

// ---------------------------------------------------------------------------
// out-proj (round-12 win): 64x64 tile, grid (64,8) = 512 WGs = 2 WG/CU =
// 8 waves/CU. Each wave owns 16 rows (acc[4], 12 MFMAs/k-step).
// ---------------------------------------------------------------------------
__global__ __launch_bounds__(256) void gemm_out_mfma(
    const ushort_t* __restrict__ Ah, const ushort_t* __restrict__ Al,
    const ushort_t* __restrict__ Wh, const ushort_t* __restrict__ Wl,
    const float* __restrict__ bias, float* __restrict__ C) {
    __shared__ ushort_t BshH[2][2048];
    __shared__ ushort_t BshL[2][2048];
    const int t = threadIdx.x, w = t >> 6, l = t & 63;
    const int ln = l & 15, quad = l >> 4;
    const int n0 = blockIdx.y * 64;
    const int m0 = blockIdx.x * 64 + w * 16;
    f32x4 acc[4] = {};
    {
        const size_t arow0 = (size_t)(m0 + ln) * INNER_;
        const int srow = t >> 2;
        const int sk   = (t & 3) << 3;
        const size_t gb = (size_t)(n0 + srow) * INNER_ + sk;
        us8 nh = *(const us8*)&Wh[gb];
        us8 nl = *(const us8*)&Wl[gb];
        *(us8*)&BshH[0][t * 8] = nh;
        *(us8*)&BshL[0][t * 8] = nl;
        int cur = 0;
        for (int k0 = 0; k0 < INNER_; k0 += 32) {
            const bool more = (k0 + 32) < INNER_;
            const size_t gnext = gb + (size_t)(more ? k0 + 32 : 0);
            nh = *(const us8*)&Wh[gnext];
            nl = *(const us8*)&Wl[gnext];
            __syncthreads();
            const int ko = k0 + quad * 8;
            bf16x8 ah0 = *(const bf16x8*)&Ah[arow0 + ko];
            bf16x8 al0 = *(const bf16x8*)&Al[arow0 + ko];
#pragma unroll
            for (int j = 0; j < 4; ++j) {
                const int slot = (((j << 4) + ln) << 5) + (quad << 3);
                bf16x8 bh = *(const bf16x8*)&BshH[cur][slot];
                bf16x8 bl = *(const bf16x8*)&BshL[cur][slot];
                acc[j] = __builtin_amdgcn_mfma_f32_16x16x32_bf16(ah0, bh, acc[j], 0, 0, 0);
                acc[j] = __builtin_amdgcn_mfma_f32_16x16x32_bf16(al0, bh, acc[j], 0, 0, 0);
                acc[j] = __builtin_amdgcn_mfma_f32_16x16x32_bf16(ah0, bl, acc[j], 0, 0, 0);
            }
            if (more) {
                *(us8*)&BshH[cur ^ 1][t * 8] = nh;
                *(us8*)&BshL[cur ^ 1][t * 8] = nl;
            }
            cur ^= 1;
        }
    }
#pragma unroll
    for (int j = 0; j < 4; ++j) {
        const int col = n0 + j * 16 + ln;
        const float bb = bias[col];
#pragma unroll
        for (int g = 0; g < 4; ++g) {
            const int token = m0 + quad * 4 + g;
            C[(size_t)token * DIM_ + col] = acc[j][g] + bb;
        }
    }
}

// ---------------------------------------------------------------------------
// MFMA kNN attention. Round 17: phase-1 K register double-buffer -- K-tile
// tt+1's 4 global loads issue BEFORE tile tt's 6 MFMAs + swizzled stores,
// hiding ~200-300 cy of L2 latency per iteration under compute. Loads,
// MFMA order, and stores are value-identical -> bitwise-identical output.
// Everything else frozen at the 217.4 us round-12/16 state.
// ---------------------------------------------------------------------------
__global__ __launch_bounds__(512)
__attribute__((amdgpu_waves_per_eu(4, 4)))
void attn_mfma(const ushort_t* __restrict__ Qh,
               const ushort_t* __restrict__ Ql,
               const ushort_t* __restrict__ Kh,
               const ushort_t* __restrict__ Kl,
               const ushort_t* __restrict__ Vt,
               ushort_t* __restrict__ Oh,
               ushort_t* __restrict__ Ol) {
    __shared__ float sdots[16 * 1024];        // 64 KB
    __shared__ float spartial[4][16][17];     // 4.25 KB j-split merge buffer

    const int t    = threadIdx.x;
    const int w    = t >> 6;        // wave 0..7
    const int l    = t & 63;
    const int ln   = l & 15;
    const int quad = l >> 4;
    const int wg   = blockIdx.x;
    const int bh   = wg & 31;       // XCD-local heads
    const int i0   = (wg >> 5) << 4;

    const size_t bhoff = (size_t)bh << 16;

    // ---- Q fragments (same for all waves; already scaled by 2^-3)
    const ushort_t* qp  = Qh + bhoff + (size_t)(i0 + ln) * 64 + (quad << 3);
    const ushort_t* qlp = Ql + bhoff + (size_t)(i0 + ln) * 64 + (quad << 3);
    bf16x8 qh0 = *(const bf16x8*)qp;
    bf16x8 qh1 = *(const bf16x8*)(qp + 32);
    bf16x8 ql0 = *(const bf16x8*)qlp;
    bf16x8 ql1 = *(const bf16x8*)(qlp + 32);

    // ---- phase-3 V base, computed early for the in-phase-2 prefetch
    const int dblk  = w & 3;
    const int jbase = (w & 4) << 7;   // 0 or 512
    const ushort_t* vp =
        Vt + bhoff + (size_t)((dblk << 4) + ln) * 1024 + (quad << 3) + jbase;
    bf16x8 vpre[8];

    // ---- Phase 1: dots. wave w covers j in [w*128, w*128+128).
    // K-tile register double-buffer: tile tt+1 loads fly under tile tt's
    // MFMAs + swizzled stores.
    bf16x8 kh0, kh1, kl0, kl1;
    {
        const int j0 = (w << 7);
        const ushort_t* kp  = Kh + bhoff + (size_t)(j0 + ln) * 64 + (quad << 3);
        const ushort_t* klp = Kl + bhoff + (size_t)(j0 + ln) * 64 + (quad << 3);
        kh0 = *(const bf16x8*)kp;
        kh1 = *(const bf16x8*)(kp + 32);
        kl0 = *(const bf16x8*)klp;
        kl1 = *(const bf16x8*)(klp + 32);
    }
#pragma unroll
    for (int tt = 0; tt < 8; ++tt) {
        bf16x8 nh0, nh1, nl0, nl1;
        if (tt < 7) {                      // issue next tile's loads NOW
            const int jn = ((w << 3) + tt + 1) << 4;
            const ushort_t* kp  = Kh + bhoff + (size_t)(jn + ln) * 64 + (quad << 3);
            const ushort_t* klp = Kl + bhoff + (size_t)(jn + ln) * 64 + (quad << 3);
            nh0 = *(const bf16x8*)kp;
            nh1 = *(const bf16x8*)(kp + 32);
            nl0 = *(const bf16x8*)klp;
            nl1 = *(const bf16x8*)(klp + 32);
        }
        const int j0 = ((w << 3) + tt) << 4;
        f32x4 acc = {0.f, 0.f, 0.f, 0.f};
        acc = __builtin_amdgcn_mfma_f32_16x16x32_bf16(qh0, kh0, acc, 0, 0, 0);
        acc = __builtin_amdgcn_mfma_f32_16x16x32_bf16(qh1, kh1, acc, 0, 0, 0);
        acc = __builtin_amdgcn_mfma_f32_16x16x32_bf16(qh0, kl0, acc, 0, 0, 0);
        acc = __builtin_amdgcn_mfma_f32_16x16x32_bf16(qh1, kl1, acc, 0, 0, 0);
        acc = __builtin_amdgcn_mfma_f32_16x16x32_bf16(ql0, kh0, acc, 0, 0, 0);
        acc = __builtin_amdgcn_mfma_f32_16x16x32_bf16(ql1, kh1, acc, 0, 0, 0);
#pragma unroll
        for (int g = 0; g < 4; ++g) {
            const int row = (quad << 2) + g;
            sdots[(row << 10) + ((j0 + ln) ^ ((row & 7) << 2))] = acc[g];
        }
        if (tt < 7) {
            kh0 = nh0; kh1 = nh1; kl0 = nl0; kl1 = nl1;
        }
    }
    __syncthreads();

    // ---- Phase 2: fused 2-row top-k + softmax + in-place bf16 P
    ushort_t* sP = (ushort_t*)sdots;
    {
        const int r0 = w << 1, r1 = r0 | 1;
        const int swz0 = (r0 & 7) << 2, swz1 = (r1 & 7) << 2;
        const float* s0 = &sdots[r0 << 10];
        const float* s1 = &sdots[r1 << 10];
        // lane l holds keys for j = 4l + 256m + i  (m=0..3, i=0..3)
        unsigned key0[16], key1[16];
        float sa0 = 0.f, sb0 = 0.f, sa1 = 0.f, sb1 = 0.f;
#pragma unroll
        for (int m = 0; m < 4; ++m) {
            f32x4 kv0 = *(const f32x4*)&s0[((l << 2) + (m << 8)) ^ swz0];
            f32x4 kv1 = *(const f32x4*)&s1[((l << 2) + (m << 8)) ^ swz1];
#pragma unroll
            for (int i = 0; i < 4; ++i) {
                key0[(m << 2) + i] = f2key(kv0[i]);
                key1[(m << 2) + i] = f2key(kv1[i]);
                sa0 += kv0[i];
                sb0 += kv0[i] * kv0[i];
                sa1 += kv1[i];
                sb1 += kv1[i] * kv1[i];
            }
        }
        // 4 independent reduction chains in one loop (latency overlap)
#pragma unroll
        for (int off = 32; off; off >>= 1) {
            sa0 += __shfl_xor(sa0, off, 64);
            sb0 += __shfl_xor(sb0, off, 64);
            sa1 += __shfl_xor(sa1, off, 64);
            sb1 += __shfl_xor(sb1, off, 64);
        }
        const float mu0 = sa0 * (1.0f / 1024.f);
        const float sg0 = sqrtf(fmaxf(sb0 * (1.0f / 1024.f) - mu0 * mu0, 1e-20f));
        const float mu1 = sa1 * (1.0f / 1024.f);
        const float sg1 = sqrtf(fmaxf(sb1 * (1.0f / 1024.f) - mu1 * mu1, 1e-20f));

        unsigned res0, res1;
        topk2(key0, key1, mu0, sg0, mu1, sg1, res0, res1);

        const float thr0 = key2f(res0), thr1 = key2f(res1);
        float pv0[16], pv1[16];
        float ls0 = 0.f, ls1 = 0.f;
#pragma unroll
        for (int m = 0; m < 16; ++m) {
            float p0 = (key0[m] >= res0) ? __expf(key2f(key0[m]) - thr0) : 0.f;
            float p1 = (key1[m] >= res1) ? __expf(key2f(key1[m]) - thr1) : 0.f;
            pv0[m] = p0;
            pv1[m] = p1;
            ls0 += p0;
            ls1 += p1;
        }
        // ---- prefetch first half of phase-3 V tiles NOW: keys are dead,
        // loads fly during the ls-reduce shuffles + P pack + barrier wait
#pragma unroll
        for (int p = 0; p < 8; ++p)
            vpre[p] = *(const bf16x8*)(vp + p * 32);
#pragma unroll
        for (int off = 32; off; off >>= 1) {
            ls0 += __shfl_xor(ls0, off, 64);
            ls1 += __shfl_xor(ls1, off, 64);
        }
        const float inv0 = 1.f / ls0, inv1 = 1.f / ls1;
        // store P (bf16, phase-3 layout): j = 4l + 256m + i
#pragma unroll
        for (int m = 0; m < 4; ++m) {
            const int g0 = ((l >> 1) + (m << 5)) ^ (r0 & 7);
            const int g1 = ((l >> 1) + (m << 5)) ^ (r1 & 7);
            ushort4 pk0 = make_ushort4(bf16_rne(pv0[(m << 2) + 0] * inv0),
                                       bf16_rne(pv0[(m << 2) + 1] * inv0),
                                       bf16_rne(pv0[(m << 2) + 2] * inv0),
                                       bf16_rne(pv0[(m << 2) + 3] * inv0));
            ushort4 pk1 = make_ushort4(bf16_rne(pv1[(m << 2) + 0] * inv1),
                                       bf16_rne(pv1[(m << 2) + 1] * inv1),
                                       bf16_rne(pv1[(m << 2) + 2] * inv1),
                                       bf16_rne(pv1[(m << 2) + 3] * inv1));
            *(ushort4*)&sP[(r0 << 11) + (g0 << 3) + ((l & 1) << 2)] = pk0;
            *(ushort4*)&sP[(r1 << 11) + (g1 << 3) + ((l & 1) << 2)] = pk1;
        }
    }
    __syncthreads();

    // ---- Phase 3: O = P @ V.  wave w: d-block (w&3), j-half (w&4 ? hi : lo)
    const int prow = ln << 11;
    const int rsw  = ln & 7;
    // issue second-half V loads, overlapped with the first 8 MFMAs
    bf16x8 vnx[8];
#pragma unroll
    for (int p = 0; p < 8; ++p)
        vnx[p] = *(const bf16x8*)(vp + 256 + p * 32);
    f32x4 oa[4] = {};
    __builtin_amdgcn_s_setprio(1);
#pragma unroll
    for (int p = 0; p < 8; ++p) {
        const int j0 = p * 32;
        const int g = ((jbase + j0) >> 3) + quad;
        bf16x8 af = *(const bf16x8*)&sP[prow + ((g ^ rsw) << 3)];
        oa[p & 3] = __builtin_amdgcn_mfma_f32_16x16x32_bf16(af, vpre[p], oa[p & 3], 0, 0, 0);
    }
#pragma unroll
    for (int p = 0; p < 8; ++p) {
        const int j0 = 256 + p * 32;
        const int g = ((jbase + j0) >> 3) + quad;
        bf16x8 af = *(const bf16x8*)&sP[prow + ((g ^ rsw) << 3)];
        oa[p & 3] = __builtin_amdgcn_mfma_f32_16x16x32_bf16(af, vnx[p], oa[p & 3], 0, 0, 0);
    }
    __builtin_amdgcn_s_setprio(0);
    f32x4 oacc = (oa[0] + oa[1]) + (oa[2] + oa[3]);

    if (w & 4) {
#pragma unroll
        for (int g = 0; g < 4; ++g)
            spartial[dblk][(quad << 2) + g][ln] = oacc[g];
    }
    __syncthreads();
    if (!(w & 4)) {
        const int b = bh >> 3, h = bh & 7;
        const size_t obase =
            ((size_t)(b << 10) + i0 + (quad << 2)) * 512 + (h << 6) + (dblk << 4) + ln;
#pragma unroll
        for (int g = 0; g < 4; ++g) {
            const float v = oacc[g] + spartial[dblk][(quad << 2) + g][ln];
            ushort_t hb = bf16_rne(v);
            Oh[obase + (size_t)g * 512] = hb;
            Ol[obase + (size_t)g * 512] = bf16_rne(v - bf16_f(hb));
        }
    }
}

extern "C" void kernel_launch(void* const* d_in, const int* in_sizes, int n_in,
                              void* d_out, int out_size, void* d_ws, size_t ws_size,
                              hipStream_t stream) {
    const float* x     = (const float*)d_in[0];
    const float* w_qkv = (const float*)d_in[1];
    const float* w_out = (const float*)d_in[2];
    const float* b_out = (const float*)d_in[3];
    float*       out   = (float*)d_out;

    const size_t ON  = (size_t)4096 * 512;
    const size_t WQT = (size_t)1536 * 512;
    const size_t WOT = (size_t)512 * 512;
    const size_t QK  = (size_t)32 * 1024 * 64;

    ushort_t* p    = (ushort_t*)d_ws;
    ushort_t* Oh   = p;            p += ON;
    ushort_t* Ol   = p;            p += ON;
    ushort_t* WqTh = p;            p += WQT;
    ushort_t* WqTl = p;            p += WQT;
    ushort_t* WoTh = p;            p += WOT;
    ushort_t* WoTl = p;            p += WOT;
    ushort_t* Qh   = p;            p += QK;
    ushort_t* Ql   = p;            p += QK;
    ushort_t* Kh   = p;            p += QK;
    ushort_t* Kl   = p;            p += QK;
    ushort_t* Vt   = p;            p += QK;   // total exactly 32 MiB

    // Xh/Xl alias Oh/Ol: live only until gemm_qkv completes; attn writes
    // Oh/Ol strictly after (stream-ordered).
    ushort_t* Xh = Oh;
    ushort_t* Xl = Ol;

    prep_split<<<dim3(2048), 256, 0, stream>>>(x, w_qkv, w_out, Xh, Xl,
                                               WqTh, WqTl, WoTh, WoTl);

    // blockIdx.x = m-block so A tiles are XCD-local
    gemm_qkv_mfma<<<dim3(4096 / 128, TRIPLE_ / 64), 256, 0, stream>>>(
        Xh, Xl, WqTh, WqTl, Qh, Ql, Kh, Kl, Vt);

    attn_mfma<<<dim3(B_ * H_ * (N_ / 16)), 512, 0, stream>>>(Qh, Ql, Kh, Kl,
                                                             Vt, Oh, Ol);

    gemm_out_mfma<<<dim3(4096 / 64, DIM_ / 64), 256, 0, stream>>>(
        Oh, Ol, WoTh, WoTl, b_out, out);
}